// Round 1
// baseline (3797.612 us; speedup 1.0000x reference)
//
#include <hip/hip_runtime.h>
#include <hip/hip_bf16.h>
#include <hip/hip_cooperative_groups.h>

namespace cg = cooperative_groups;

typedef unsigned short ushort_t;
typedef __bf16 bf16x8 __attribute__((ext_vector_type(8)));
typedef float floatx4 __attribute__((ext_vector_type(4)));
typedef unsigned short us8 __attribute__((ext_vector_type(8)));
typedef unsigned short us4 __attribute__((ext_vector_type(4)));

#define B_SZ   128
#define T_SZ   64
#define E_SZ   512
#define H_SZ   1024
#define G3     3072          // 3*H
#define MA     8192          // B*T
#define KA     512           // E

__device__ __forceinline__ float bf2f(unsigned short u) {
    return __uint_as_float(((unsigned int)u) << 16);
}
__device__ __forceinline__ unsigned short f2bf(float f) {
    unsigned int u = __float_as_uint(f);
    u += 0x7fffu + ((u >> 16) & 1u);       // round-to-nearest-even
    return (unsigned short)(u >> 16);
}
__device__ __forceinline__ float fsigmoid(float x) { return 1.0f / (1.0f + __expf(-x)); }
__device__ __forceinline__ float ftanh(float x) {
    float ax = fabsf(x);
    float e  = __expf(2.0f * ax);
    float t  = 1.0f - 2.0f / (e + 1.0f);   // graceful at overflow: -> 1
    return copysignf(t, x);
}
__device__ __forceinline__ void gload_lds16(const ushort_t* g, ushort_t* l) {
    __builtin_amdgcn_global_load_lds((const __attribute__((address_space(1))) unsigned int*)g,
                                     (__attribute__((address_space(3))) unsigned int*)l, 16, 0, 0);
}
__device__ __forceinline__ floatx4 mfma16(bf16x8 a, bf16x8 b, floatx4 c) {
    return __builtin_amdgcn_mfma_f32_16x16x32_bf16(a, b, c, 0, 0, 0);
}

// ---------------------------------------------------------------------------
// Prep: f32->bf16 weight conversion, embedding gather+convert, zero h0 buffer.
// ---------------------------------------------------------------------------
__global__ __launch_bounds__(256) void k_prep(const float* __restrict__ wih,
                                              const float* __restrict__ whh,
                                              const float* __restrict__ emb,
                                              const int*   __restrict__ sent,
                                              ushort_t* __restrict__ wih_b,
                                              ushort_t* __restrict__ whh_b,
                                              ushort_t* __restrict__ e_b,
                                              ushort_t* __restrict__ hbuf) {
    const int N1 = G3 * E_SZ / 4;        // 393216   w_ih quads
    const int N2 = G3 * H_SZ / 4;        // 786432   w_hh quads
    const int N3 = MA * E_SZ / 4;        // 1048576  gathered emb quads
    const int N4 = B_SZ * H_SZ / 4;      // 32768    h0 quads (buffer 0 only)
    const int total = N1 + N2 + N3 + N4;
    for (int i = blockIdx.x * blockDim.x + threadIdx.x; i < total;
         i += gridDim.x * blockDim.x) {
        if (i < N1) {
            float4 v = ((const float4*)wih)[i];
            us4 o = { f2bf(v.x), f2bf(v.y), f2bf(v.z), f2bf(v.w) };
            *(us4*)&wih_b[i * 4] = o;
        } else if (i < N1 + N2) {
            int k = i - N1;
            float4 v = ((const float4*)whh)[k];
            us4 o = { f2bf(v.x), f2bf(v.y), f2bf(v.z), f2bf(v.w) };
            *(us4*)&whh_b[k * 4] = o;
        } else if (i < N1 + N2 + N3) {
            int k = i - N1 - N2;
            int m  = k >> 7;              // row in [0, 8192)
            int e4 = k & 127;             // float4 index within row
            float4 v = ((const float4*)(emb + (size_t)sent[m] * E_SZ))[e4];
            us4 o = { f2bf(v.x), f2bf(v.y), f2bf(v.z), f2bf(v.w) };
            *(us4*)&e_b[k * 4] = o;
        } else {
            int k = i - N1 - N2 - N3;
            us4 z = { 0, 0, 0, 0 };
            *(us4*)&hbuf[k * 4] = z;
        }
    }
}

// ---------------------------------------------------------------------------
// Phase A: xg[m][g] = E[m][:] . Wih[g][:] + bih[g]   (bt-GEMM, m97 structure)
// grid (64, 24), 256 threads, 128x128 tile, BK=32.
// ---------------------------------------------------------------------------
__global__ __launch_bounds__(256) void k_gemm_xg(const ushort_t* __restrict__ A,
                                                 const ushort_t* __restrict__ Bm,
                                                 const float* __restrict__ bih,
                                                 ushort_t* __restrict__ xg) {
    __shared__ __align__(16) ushort_t Al[128 * 32];
    __shared__ __align__(16) ushort_t Bl[128 * 32];
    const int tid = threadIdx.x;
    const int m0 = blockIdx.x * 128, n0 = blockIdx.y * 128;
    const int wid = tid >> 6, lane = tid & 63;
    const int wm = wid & 1, wn = wid >> 1;
    const int lr = lane & 15, lq = lane >> 4;
    floatx4 acc[4][4] = {};
    for (int kb = 0; kb < KA / 32; ++kb) {
        const int k0 = kb * 32;
        #pragma unroll
        for (int j = 0; j < 2; ++j) {
            int c = j * 256 + tid;          // 512 16B chunks per matrix
            int row = c >> 2, k8 = c & 3;
            gload_lds16(A  + (size_t)(m0 + row) * KA + k0 + k8 * 8, &Al[c * 8]);
            gload_lds16(Bm + (size_t)(n0 + row) * KA + k0 + k8 * 8, &Bl[c * 8]);
        }
        __syncthreads();
        bf16x8 af[4], bf[4];
        #pragma unroll
        for (int i = 0; i < 4; ++i) af[i] = *(const bf16x8*)&Al[(wm * 64 + i * 16 + lr) * 32 + lq * 8];
        #pragma unroll
        for (int j = 0; j < 4; ++j) bf[j] = *(const bf16x8*)&Bl[(wn * 64 + j * 16 + lr) * 32 + lq * 8];
        #pragma unroll
        for (int i = 0; i < 4; ++i)
            #pragma unroll
            for (int j = 0; j < 4; ++j)
                acc[i][j] = mfma16(af[i], bf[j], acc[i][j]);
        __syncthreads();
    }
    #pragma unroll
    for (int i = 0; i < 4; ++i) {
        int grow = m0 + wm * 64 + i * 16 + lq * 4;
        #pragma unroll
        for (int j = 0; j < 4; ++j) {
            int gcol = n0 + wn * 64 + j * 16 + lr;
            float bv = bih[gcol];
            #pragma unroll
            for (int r = 0; r < 4; ++r)
                xg[(size_t)(grow + r) * G3 + gcol] = f2bf(acc[i][j][r] + bv);
        }
    }
}

// ---------------------------------------------------------------------------
// Recurrence: cooperative, 256 WGs x 256 thr. WG = (slab s: 16 h-cols, quarter
// q: 32 batch rows). w_hh fragments live in VGPRs (K split 4-ways over waves);
// h staged per step into swizzled LDS; partial-K reduce reuses the LDS.
// One grid.sync per step; h double-buffered.
// ---------------------------------------------------------------------------
__global__ __launch_bounds__(256) void k_recur(const ushort_t* __restrict__ xg,
                                               const ushort_t* __restrict__ whh,
                                               const float* __restrict__ bhh,
                                               const int*   __restrict__ slen,
                                               ushort_t* __restrict__ hbuf,
                                               float* __restrict__ finalbuf) {
    __shared__ __align__(16) unsigned char smem[65536];
    ushort_t* Al = (ushort_t*)smem;          // 32 x 1024 bf16, xor-swizzled
    float*    P  = (float*)smem;             // reused: 4x2x3x16x16 f32 partials
    cg::grid_group grid = cg::this_grid();
    const int tid = threadIdx.x, lane = tid & 63, kq = tid >> 6;
    const int s = blockIdx.x >> 2, q = blockIdx.x & 3;
    const int lr = lane & 15, lq = lane >> 4;

    // --- load this wave's w_hh fragments into registers (static across steps)
    bf16x8 Bf[3][8];
    #pragma unroll
    for (int nt = 0; nt < 3; ++nt) {
        const ushort_t* wrow = whh + (size_t)(nt * H_SZ + s * 16 + lr) * H_SZ;
        #pragma unroll
        for (int i = 0; i < 8; ++i)
            Bf[nt][i] = *(const bf16x8*)(wrow + kq * 256 + i * 32 + lq * 8);
    }

    for (int t = 0; t < 64; ++t) {
        const ushort_t* hrd = hbuf + (t & 1) * (B_SZ * H_SZ);
        ushort_t*       hwr = hbuf + ((t + 1) & 1) * (B_SZ * H_SZ);
        // --- stage h rows [32q, 32q+32) x 1024 into LDS (xor swizzle on 16B chunks)
        #pragma unroll
        for (int it = 0; it < 16; ++it) {
            int c = it * 256 + tid;           // 0..4095
            int row = c >> 7, cc = c & 127;
            us8 v = *(const us8*)(hrd + (size_t)(32 * q + row) * H_SZ + cc * 8);
            *(us8*)&Al[(row * 128 + (cc ^ (row & 7))) * 8] = v;
        }
        __syncthreads();
        // --- GEMM: this wave handles K slice [256*kq, 256*kq+256)
        floatx4 acc[2][3] = {};
        #pragma unroll
        for (int i = 0; i < 8; ++i) {
            int cb = 32 * kq + 4 * i + lq;    // 16B chunk index within a row
            int r0 = lr, r1 = 16 + lr;
            bf16x8 a0 = *(const bf16x8*)&Al[(r0 * 128 + (cb ^ (r0 & 7))) * 8];
            bf16x8 a1 = *(const bf16x8*)&Al[(r1 * 128 + (cb ^ (r1 & 7))) * 8];
            #pragma unroll
            for (int nt = 0; nt < 3; ++nt) {
                acc[0][nt] = mfma16(a0, Bf[nt][i], acc[0][nt]);
                acc[1][nt] = mfma16(a1, Bf[nt][i], acc[1][nt]);
            }
        }
        __syncthreads();                      // done with Al; reuse as P
        // --- write K-partials: P[kq][mt][nt][rowInTile][col]
        #pragma unroll
        for (int mt = 0; mt < 2; ++mt)
            #pragma unroll
            for (int nt = 0; nt < 3; ++nt)
                #pragma unroll
                for (int r = 0; r < 4; ++r)
                    P[(kq * 6 + mt * 3 + nt) * 256 + (lq * 4 + r) * 16 + lr] = acc[mt][nt][r];
        __syncthreads();
        // --- gate phase: 512 h elements, 2 per thread
        #pragma unroll
        for (int e2 = 0; e2 < 2; ++e2) {
            int e  = e2 * 256 + tid;          // 0..511
            int bl = e >> 4, j = e & 15;
            int mt = bl >> 4, ri = bl & 15;
            float hg[3];
            #pragma unroll
            for (int nt = 0; nt < 3; ++nt) {
                int base = (mt * 3 + nt) * 256 + ri * 16 + j;
                hg[nt] = P[base] + P[base + 6 * 256] + P[base + 12 * 256] + P[base + 18 * 256];
            }
            int bg  = 32 * q + bl;
            int col = s * 16 + j;
            size_t xb = (size_t)(bg * T_SZ + t) * G3 + col;
            float xr = bf2f(xg[xb]);
            float xz = bf2f(xg[xb + 1024]);
            float xn = bf2f(xg[xb + 2048]);
            float rr = fsigmoid(xr + hg[0] + bhh[col]);
            float zz = fsigmoid(xz + hg[1] + bhh[1024 + col]);
            float nn = ftanh(xn + rr * (hg[2] + bhh[2048 + col]));
            float hold = bf2f(hrd[(size_t)bg * H_SZ + col]);
            float hnew = (1.0f - zz) * nn + zz * hold;
            hwr[(size_t)bg * H_SZ + col] = f2bf(hnew);
            if (slen[bg] - 1 == t) finalbuf[(size_t)bg * H_SZ + col] = hnew;
        }
        __threadfence();
        grid.sync();
    }
}

// ---------------------------------------------------------------------------
// Final L2-normalize per batch row.
// ---------------------------------------------------------------------------
__global__ __launch_bounds__(256) void k_norm(const float* __restrict__ finalbuf,
                                              float* __restrict__ out) {
    const int b = blockIdx.x, tid = threadIdx.x;
    const float4 v = ((const float4*)(finalbuf + (size_t)b * H_SZ))[tid];
    float ss = v.x * v.x + v.y * v.y + v.z * v.z + v.w * v.w;
    #pragma unroll
    for (int off = 32; off > 0; off >>= 1) ss += __shfl_down(ss, off);
    __shared__ float red[4];
    const int wid = tid >> 6, lane = tid & 63;
    if (lane == 0) red[wid] = ss;
    __syncthreads();
    const float total = red[0] + red[1] + red[2] + red[3];
    const float inv = 1.0f / sqrtf(total);
    float4 o;
    o.x = v.x * inv; o.y = v.y * inv; o.z = v.z * inv; o.w = v.w * inv;
    ((float4*)(out + (size_t)b * H_SZ))[tid] = o;
}

extern "C" void kernel_launch(void* const* d_in, const int* in_sizes, int n_in,
                              void* d_out, int out_size, void* d_ws, size_t ws_size,
                              hipStream_t stream) {
    const int*   sent = (const int*)d_in[0];
    const int*   slen = (const int*)d_in[1];
    const float* emb  = (const float*)d_in[2];
    const float* wih  = (const float*)d_in[3];
    const float* whh  = (const float*)d_in[4];
    const float* bih  = (const float*)d_in[5];
    const float* bhh  = (const float*)d_in[6];
    float* out = (float*)d_out;
    char* ws = (char*)d_ws;

    // workspace layout (bytes)
    ushort_t* e_b      = (ushort_t*)(ws);                 //  8,388,608  (8192x512 bf16)
    ushort_t* wih_b    = (ushort_t*)(ws + 8388608);       //  3,145,728
    ushort_t* whh_b    = (ushort_t*)(ws + 11534336);      //  6,291,456
    ushort_t* xg       = (ushort_t*)(ws + 17825792);      // 50,331,648  (8192x3072 bf16)
    ushort_t* hbuf     = (ushort_t*)(ws + 68157440);      //    524,288  (2 x 128x1024 bf16)
    float*    finalbuf = (float*)   (ws + 68681728);      //    524,288  (128x1024 f32)

    hipLaunchKernelGGL(k_prep, dim3(1024), dim3(256), 0, stream,
                       wih, whh, emb, sent, wih_b, whh_b, e_b, hbuf);
    hipLaunchKernelGGL(k_gemm_xg, dim3(64, 24), dim3(256), 0, stream,
                       e_b, wih_b, bih, xg);
    void* args[] = { (void*)&xg, (void*)&whh_b, (void*)&bhh,
                     (void*)&slen, (void*)&hbuf, (void*)&finalbuf };
    hipLaunchCooperativeKernel((void*)k_recur, dim3(256), dim3(256), args, 0, stream);
    hipLaunchKernelGGL(k_norm, dim3(128), dim3(256), 0, stream, finalbuf, out);
}

// Round 2
// 3112.513 us; speedup vs baseline: 1.2201x; 1.2201x over previous
//
#include <hip/hip_runtime.h>
#include <hip/hip_bf16.h>

typedef unsigned short ushort_t;
typedef __bf16 bf16x8 __attribute__((ext_vector_type(8)));
typedef float floatx4 __attribute__((ext_vector_type(4)));
typedef unsigned short us8 __attribute__((ext_vector_type(8)));
typedef unsigned short us4 __attribute__((ext_vector_type(4)));

#define B_SZ   128
#define T_SZ   64
#define E_SZ   512
#define H_SZ   1024
#define G3     3072          // 3*H
#define MA     8192          // B*T
#define KA     512           // E
#define NWG    256

__device__ __forceinline__ float bf2f(unsigned short u) {
    return __uint_as_float(((unsigned int)u) << 16);
}
__device__ __forceinline__ unsigned short f2bf(float f) {
    unsigned int u = __float_as_uint(f);
    u += 0x7fffu + ((u >> 16) & 1u);       // round-to-nearest-even
    return (unsigned short)(u >> 16);
}
__device__ __forceinline__ float fsigmoid(float x) { return 1.0f / (1.0f + __expf(-x)); }
__device__ __forceinline__ float ftanh(float x) {
    float ax = fabsf(x);
    float e  = __expf(2.0f * ax);
    float t  = 1.0f - 2.0f / (e + 1.0f);   // graceful at overflow: -> 1
    return copysignf(t, x);
}
__device__ __forceinline__ void gload_lds16(const ushort_t* g, ushort_t* l) {
    __builtin_amdgcn_global_load_lds((const __attribute__((address_space(1))) unsigned int*)g,
                                     (__attribute__((address_space(3))) unsigned int*)l, 16, 0, 0);
}
__device__ __forceinline__ floatx4 mfma16(bf16x8 a, bf16x8 b, floatx4 c) {
    return __builtin_amdgcn_mfma_f32_16x16x32_bf16(a, b, c, 0, 0, 0);
}

// Custom grid barrier: monotonic counter, arrival by thread 0 of each WG,
// relaxed agent-scope spin with s_sleep backoff. __threadfence() provides
// the same release/acquire (L2 wb/inv, cross-XCD) semantics the original
// grid.sync() path had — only the rendezvous is replaced.
__device__ __forceinline__ void grid_barrier(unsigned int* bar, unsigned int target) {
    __threadfence();                       // release: h writes visible device-wide
    __syncthreads();
    if (threadIdx.x == 0) {
        __hip_atomic_fetch_add(bar, 1u, __ATOMIC_RELAXED, __HIP_MEMORY_SCOPE_AGENT);
        while (__hip_atomic_load(bar, __ATOMIC_RELAXED, __HIP_MEMORY_SCOPE_AGENT) < target)
            __builtin_amdgcn_s_sleep(1);
    }
    __syncthreads();
    __threadfence();                       // acquire: invalidate stale L1/L2
}

// ---------------------------------------------------------------------------
// Prep: f32->bf16 weight conversion, embedding gather+convert, zero h0 buffer.
// ---------------------------------------------------------------------------
__global__ __launch_bounds__(256) void k_prep(const float* __restrict__ wih,
                                              const float* __restrict__ whh,
                                              const float* __restrict__ emb,
                                              const int*   __restrict__ sent,
                                              ushort_t* __restrict__ wih_b,
                                              ushort_t* __restrict__ whh_b,
                                              ushort_t* __restrict__ e_b,
                                              ushort_t* __restrict__ hbuf) {
    const int N1 = G3 * E_SZ / 4;        // 393216   w_ih quads
    const int N2 = G3 * H_SZ / 4;        // 786432   w_hh quads
    const int N3 = MA * E_SZ / 4;        // 1048576  gathered emb quads
    const int N4 = B_SZ * H_SZ / 4;      // 32768    h0 quads (buffer 0 only)
    const int total = N1 + N2 + N3 + N4;
    for (int i = blockIdx.x * blockDim.x + threadIdx.x; i < total;
         i += gridDim.x * blockDim.x) {
        if (i < N1) {
            float4 v = ((const float4*)wih)[i];
            us4 o = { f2bf(v.x), f2bf(v.y), f2bf(v.z), f2bf(v.w) };
            *(us4*)&wih_b[i * 4] = o;
        } else if (i < N1 + N2) {
            int k = i - N1;
            float4 v = ((const float4*)whh)[k];
            us4 o = { f2bf(v.x), f2bf(v.y), f2bf(v.z), f2bf(v.w) };
            *(us4*)&whh_b[k * 4] = o;
        } else if (i < N1 + N2 + N3) {
            int k = i - N1 - N2;
            int m  = k >> 7;              // row in [0, 8192)
            int e4 = k & 127;             // float4 index within row
            float4 v = ((const float4*)(emb + (size_t)sent[m] * E_SZ))[e4];
            us4 o = { f2bf(v.x), f2bf(v.y), f2bf(v.z), f2bf(v.w) };
            *(us4*)&e_b[k * 4] = o;
        } else {
            int k = i - N1 - N2 - N3;
            us4 z = { 0, 0, 0, 0 };
            *(us4*)&hbuf[k * 4] = z;
        }
    }
}

// Zero the barrier counter. Runs between k_gemm_xg (last reader of e_b, whose
// first bytes the counter overlays) and k_recur.
__global__ void k_zero_bar(unsigned int* bar) { *bar = 0u; }

// ---------------------------------------------------------------------------
// Phase A: xg[m][g] = E[m][:] . Wih[g][:] + bih[g]   (bt-GEMM, m97 structure)
// grid (64, 24), 256 threads, 128x128 tile, BK=32.
// ---------------------------------------------------------------------------
__global__ __launch_bounds__(256) void k_gemm_xg(const ushort_t* __restrict__ A,
                                                 const ushort_t* __restrict__ Bm,
                                                 const float* __restrict__ bih,
                                                 ushort_t* __restrict__ xg) {
    __shared__ __align__(16) ushort_t Al[128 * 32];
    __shared__ __align__(16) ushort_t Bl[128 * 32];
    const int tid = threadIdx.x;
    const int m0 = blockIdx.x * 128, n0 = blockIdx.y * 128;
    const int wid = tid >> 6, lane = tid & 63;
    const int wm = wid & 1, wn = wid >> 1;
    const int lr = lane & 15, lq = lane >> 4;
    floatx4 acc[4][4] = {};
    for (int kb = 0; kb < KA / 32; ++kb) {
        const int k0 = kb * 32;
        #pragma unroll
        for (int j = 0; j < 2; ++j) {
            int c = j * 256 + tid;          // 512 16B chunks per matrix
            int row = c >> 2, k8 = c & 3;
            gload_lds16(A  + (size_t)(m0 + row) * KA + k0 + k8 * 8, &Al[c * 8]);
            gload_lds16(Bm + (size_t)(n0 + row) * KA + k0 + k8 * 8, &Bl[c * 8]);
        }
        __syncthreads();
        bf16x8 af[4], bf[4];
        #pragma unroll
        for (int i = 0; i < 4; ++i) af[i] = *(const bf16x8*)&Al[(wm * 64 + i * 16 + lr) * 32 + lq * 8];
        #pragma unroll
        for (int j = 0; j < 4; ++j) bf[j] = *(const bf16x8*)&Bl[(wn * 64 + j * 16 + lr) * 32 + lq * 8];
        #pragma unroll
        for (int i = 0; i < 4; ++i)
            #pragma unroll
            for (int j = 0; j < 4; ++j)
                acc[i][j] = mfma16(af[i], bf[j], acc[i][j]);
        __syncthreads();
    }
    #pragma unroll
    for (int i = 0; i < 4; ++i) {
        int grow = m0 + wm * 64 + i * 16 + lq * 4;
        #pragma unroll
        for (int j = 0; j < 4; ++j) {
            int gcol = n0 + wn * 64 + j * 16 + lr;
            float bv = bih[gcol];
            #pragma unroll
            for (int r = 0; r < 4; ++r)
                xg[(size_t)(grow + r) * G3 + gcol] = f2bf(acc[i][j][r] + bv);
        }
    }
}

// ---------------------------------------------------------------------------
// Recurrence: cooperative, 256 WGs x 256 thr. WG = (slab s: 16 h-cols, quarter
// q: 32 batch rows). w_hh fragments live in VGPRs (K split 4-ways over waves);
// h staged per step into swizzled LDS; partial-K reduce reuses the LDS.
// One custom grid barrier per step (skipped on the last); h double-buffered.
// ---------------------------------------------------------------------------
__global__ __launch_bounds__(256) void k_recur(const ushort_t* __restrict__ xg,
                                               const ushort_t* __restrict__ whh,
                                               const float* __restrict__ bhh,
                                               const int*   __restrict__ slen,
                                               ushort_t* __restrict__ hbuf,
                                               float* __restrict__ finalbuf,
                                               unsigned int* __restrict__ bar) {
    __shared__ __align__(16) unsigned char smem[65536];
    ushort_t* Al = (ushort_t*)smem;          // 32 x 1024 bf16, xor-swizzled
    float*    P  = (float*)smem;             // reused: 4x2x3x16x16 f32 partials
    const int tid = threadIdx.x, lane = tid & 63, kq = tid >> 6;
    const int s = blockIdx.x >> 2, q = blockIdx.x & 3;
    const int lr = lane & 15, lq = lane >> 4;

    // --- load this wave's w_hh fragments into registers (static across steps)
    bf16x8 Bf[3][8];
    #pragma unroll
    for (int nt = 0; nt < 3; ++nt) {
        const ushort_t* wrow = whh + (size_t)(nt * H_SZ + s * 16 + lr) * H_SZ;
        #pragma unroll
        for (int i = 0; i < 8; ++i)
            Bf[nt][i] = *(const bf16x8*)(wrow + kq * 256 + i * 32 + lq * 8);
    }

    for (int t = 0; t < 64; ++t) {
        const ushort_t* hrd = hbuf + (t & 1) * (B_SZ * H_SZ);
        ushort_t*       hwr = hbuf + ((t + 1) & 1) * (B_SZ * H_SZ);
        // --- stage h rows [32q, 32q+32) x 1024 into LDS (xor swizzle on 16B chunks)
        #pragma unroll
        for (int it = 0; it < 16; ++it) {
            int c = it * 256 + tid;           // 0..4095
            int row = c >> 7, cc = c & 127;
            us8 v = *(const us8*)(hrd + (size_t)(32 * q + row) * H_SZ + cc * 8);
            *(us8*)&Al[(row * 128 + (cc ^ (row & 7))) * 8] = v;
        }
        __syncthreads();
        // --- GEMM: this wave handles K slice [256*kq, 256*kq+256)
        floatx4 acc[2][3] = {};
        #pragma unroll
        for (int i = 0; i < 8; ++i) {
            int cb = 32 * kq + 4 * i + lq;    // 16B chunk index within a row
            int r0 = lr, r1 = 16 + lr;
            bf16x8 a0 = *(const bf16x8*)&Al[(r0 * 128 + (cb ^ (r0 & 7))) * 8];
            bf16x8 a1 = *(const bf16x8*)&Al[(r1 * 128 + (cb ^ (r1 & 7))) * 8];
            #pragma unroll
            for (int nt = 0; nt < 3; ++nt) {
                acc[0][nt] = mfma16(a0, Bf[nt][i], acc[0][nt]);
                acc[1][nt] = mfma16(a1, Bf[nt][i], acc[1][nt]);
            }
        }
        // --- read h_old for this thread's two gate elements from LDS (still valid)
        float holdv[2];
        #pragma unroll
        for (int e2 = 0; e2 < 2; ++e2) {
            int e  = e2 * 256 + tid;
            int bl = e >> 4, j = e & 15;
            int cc = s * 2 + (j >> 3);
            holdv[e2] = bf2f(Al[(bl * 128 + (cc ^ (bl & 7))) * 8 + (j & 7)]);
        }
        __syncthreads();                      // done with Al; reuse as P
        // --- write K-partials: P[kq][mt][nt][rowInTile][col]
        #pragma unroll
        for (int mt = 0; mt < 2; ++mt)
            #pragma unroll
            for (int nt = 0; nt < 3; ++nt)
                #pragma unroll
                for (int r = 0; r < 4; ++r)
                    P[(kq * 6 + mt * 3 + nt) * 256 + (lq * 4 + r) * 16 + lr] = acc[mt][nt][r];
        __syncthreads();
        // --- gate phase: 512 h elements, 2 per thread
        #pragma unroll
        for (int e2 = 0; e2 < 2; ++e2) {
            int e  = e2 * 256 + tid;          // 0..511
            int bl = e >> 4, j = e & 15;
            int mt = bl >> 4, ri = bl & 15;
            float hg[3];
            #pragma unroll
            for (int nt = 0; nt < 3; ++nt) {
                int base = (mt * 3 + nt) * 256 + ri * 16 + j;
                hg[nt] = P[base] + P[base + 6 * 256] + P[base + 12 * 256] + P[base + 18 * 256];
            }
            int bg  = 32 * q + bl;
            int col = s * 16 + j;
            size_t xb = (size_t)(bg * T_SZ + t) * G3 + col;
            float xr = bf2f(xg[xb]);
            float xz = bf2f(xg[xb + 1024]);
            float xn = bf2f(xg[xb + 2048]);
            float rr = fsigmoid(xr + hg[0] + bhh[col]);
            float zz = fsigmoid(xz + hg[1] + bhh[1024 + col]);
            float nn = ftanh(xn + rr * (hg[2] + bhh[2048 + col]));
            float hnew = (1.0f - zz) * nn + zz * holdv[e2];
            hwr[(size_t)bg * H_SZ + col] = f2bf(hnew);
            if (slen[bg] - 1 == t) finalbuf[(size_t)bg * H_SZ + col] = hnew;
        }
        if (t != 63) grid_barrier(bar, (unsigned int)(NWG * (t + 1)));
    }
}

// ---------------------------------------------------------------------------
// Final L2-normalize per batch row.
// ---------------------------------------------------------------------------
__global__ __launch_bounds__(256) void k_norm(const float* __restrict__ finalbuf,
                                              float* __restrict__ out) {
    const int b = blockIdx.x, tid = threadIdx.x;
    const float4 v = ((const float4*)(finalbuf + (size_t)b * H_SZ))[tid];
    float ss = v.x * v.x + v.y * v.y + v.z * v.z + v.w * v.w;
    #pragma unroll
    for (int off = 32; off > 0; off >>= 1) ss += __shfl_down(ss, off);
    __shared__ float red[4];
    const int wid = tid >> 6, lane = tid & 63;
    if (lane == 0) red[wid] = ss;
    __syncthreads();
    const float total = red[0] + red[1] + red[2] + red[3];
    const float inv = 1.0f / sqrtf(total);
    float4 o;
    o.x = v.x * inv; o.y = v.y * inv; o.z = v.z * inv; o.w = v.w * inv;
    ((float4*)(out + (size_t)b * H_SZ))[tid] = o;
}

extern "C" void kernel_launch(void* const* d_in, const int* in_sizes, int n_in,
                              void* d_out, int out_size, void* d_ws, size_t ws_size,
                              hipStream_t stream) {
    const int*   sent = (const int*)d_in[0];
    const int*   slen = (const int*)d_in[1];
    const float* emb  = (const float*)d_in[2];
    const float* wih  = (const float*)d_in[3];
    const float* whh  = (const float*)d_in[4];
    const float* bih  = (const float*)d_in[5];
    const float* bhh  = (const float*)d_in[6];
    float* out = (float*)d_out;
    char* ws = (char*)d_ws;

    // workspace layout (bytes)
    ushort_t* e_b      = (ushort_t*)(ws);                 //  8,388,608  (8192x512 bf16)
    ushort_t* wih_b    = (ushort_t*)(ws + 8388608);       //  3,145,728
    ushort_t* whh_b    = (ushort_t*)(ws + 11534336);      //  6,291,456
    ushort_t* xg       = (ushort_t*)(ws + 17825792);      // 50,331,648  (8192x3072 bf16)
    ushort_t* hbuf     = (ushort_t*)(ws + 68157440);      //    524,288  (2 x 128x1024 bf16)
    float*    finalbuf = (float*)   (ws + 68681728);      //    524,288  (128x1024 f32)
    // barrier counter overlays e_b[0..1] — e_b is dead after k_gemm_xg
    unsigned int* bar  = (unsigned int*)(ws);

    hipLaunchKernelGGL(k_prep, dim3(1024), dim3(256), 0, stream,
                       wih, whh, emb, sent, wih_b, whh_b, e_b, hbuf);
    hipLaunchKernelGGL(k_gemm_xg, dim3(64, 24), dim3(256), 0, stream,
                       e_b, wih_b, bih, xg);
    hipLaunchKernelGGL(k_zero_bar, dim3(1), dim3(1), 0, stream, bar);
    void* args[] = { (void*)&xg, (void*)&whh_b, (void*)&bhh,
                     (void*)&slen, (void*)&hbuf, (void*)&finalbuf, (void*)&bar };
    hipLaunchCooperativeKernel((void*)k_recur, dim3(256), dim3(256), args, 0, stream);
    hipLaunchKernelGGL(k_norm, dim3(128), dim3(256), 0, stream, finalbuf, out);
}

// Round 6
// 3059.102 us; speedup vs baseline: 1.2414x; 1.0175x over previous
//
#include <hip/hip_runtime.h>
#include <hip/hip_bf16.h>

typedef unsigned short ushort_t;
typedef __bf16 bf16x8 __attribute__((ext_vector_type(8)));
typedef float floatx4 __attribute__((ext_vector_type(4)));
typedef unsigned short us8 __attribute__((ext_vector_type(8)));
typedef unsigned short us4 __attribute__((ext_vector_type(4)));

#define B_SZ   128
#define T_SZ   64
#define E_SZ   512
#define H_SZ   1024
#define G3     3072          // 3*H
#define MA     8192          // B*T
#define KA     512           // E
#define NWG    256

__device__ __forceinline__ float bf2f(unsigned short u) {
    return __uint_as_float(((unsigned int)u) << 16);
}
__device__ __forceinline__ unsigned short f2bf(float f) {
    unsigned int u = __float_as_uint(f);
    u += 0x7fffu + ((u >> 16) & 1u);       // round-to-nearest-even
    return (unsigned short)(u >> 16);
}
__device__ __forceinline__ float fsigmoid(float x) { return 1.0f / (1.0f + __expf(-x)); }
__device__ __forceinline__ float ftanh(float x) {
    float ax = fabsf(x);
    float e  = __expf(2.0f * ax);
    float t  = 1.0f - 2.0f / (e + 1.0f);   // graceful at overflow: -> 1
    return copysignf(t, x);
}
__device__ __forceinline__ void gload_lds16(const ushort_t* g, ushort_t* l) {
    __builtin_amdgcn_global_load_lds((const __attribute__((address_space(1))) unsigned int*)g,
                                     (__attribute__((address_space(3))) unsigned int*)l, 16, 0, 0);
}
__device__ __forceinline__ floatx4 mfma16(bf16x8 a, bf16x8 b, floatx4 c) {
    return __builtin_amdgcn_mfma_f32_16x16x32_bf16(a, b, c, 0, 0, 0);
}

// Custom grid barrier — EXACTLY the R2-proven semantics (threadfence on both
// sides, full-grid monotonic counter, agent-scope atomics). The only change
// vs R2 is that the kernel is now launched as a PLAIN kernel: co-residency
// of all 256 WGs is guaranteed by capacity (LDS 64 KB -> <=2 blocks/CU ->
// 256 blocks always simultaneously resident on 256 CUs), so the spin cannot
// deadlock. R3/R4/R5's identical-poison failures are attributed to the
// hipLaunchCooperativeKernel call silently failing (unchecked error ->
// k_recur never enqueued -> finalbuf stayed 0xAA -> absmax exactly
// max|ref|+1/32 = 0.1265 in all three rounds).
__device__ __forceinline__ void grid_barrier(unsigned int* bar, unsigned int target) {
    __threadfence();                       // release: h writes drained (wbl2)
    __syncthreads();
    if (threadIdx.x == 0) {
        __hip_atomic_fetch_add(bar, 1u, __ATOMIC_RELAXED, __HIP_MEMORY_SCOPE_AGENT);
        while (__hip_atomic_load(bar, __ATOMIC_RELAXED, __HIP_MEMORY_SCOPE_AGENT) < target)
            __builtin_amdgcn_s_sleep(1);
    }
    __syncthreads();
    __threadfence();                       // acquire: invalidate stale L1/L2
}

// ---------------------------------------------------------------------------
// Prep: f32->bf16 weight conversion, embedding gather+convert, zero h0 buffer.
// ---------------------------------------------------------------------------
__global__ __launch_bounds__(256) void k_prep(const float* __restrict__ wih,
                                              const float* __restrict__ whh,
                                              const float* __restrict__ emb,
                                              const int*   __restrict__ sent,
                                              ushort_t* __restrict__ wih_b,
                                              ushort_t* __restrict__ whh_b,
                                              ushort_t* __restrict__ e_b,
                                              ushort_t* __restrict__ hbuf) {
    const int N1 = G3 * E_SZ / 4;        // 393216   w_ih quads
    const int N2 = G3 * H_SZ / 4;        // 786432   w_hh quads
    const int N3 = MA * E_SZ / 4;        // 1048576  gathered emb quads
    const int N4 = B_SZ * H_SZ / 4;      // 32768    h0 quads (buffer 0 only)
    const int total = N1 + N2 + N3 + N4;
    for (int i = blockIdx.x * blockDim.x + threadIdx.x; i < total;
         i += gridDim.x * blockDim.x) {
        if (i < N1) {
            float4 v = ((const float4*)wih)[i];
            us4 o = { f2bf(v.x), f2bf(v.y), f2bf(v.z), f2bf(v.w) };
            *(us4*)&wih_b[i * 4] = o;
        } else if (i < N1 + N2) {
            int k = i - N1;
            float4 v = ((const float4*)whh)[k];
            us4 o = { f2bf(v.x), f2bf(v.y), f2bf(v.z), f2bf(v.w) };
            *(us4*)&whh_b[k * 4] = o;
        } else if (i < N1 + N2 + N3) {
            int k = i - N1 - N2;
            int m  = k >> 7;              // row in [0, 8192)
            int e4 = k & 127;             // float4 index within row
            float4 v = ((const float4*)(emb + (size_t)sent[m] * E_SZ))[e4];
            us4 o = { f2bf(v.x), f2bf(v.y), f2bf(v.z), f2bf(v.w) };
            *(us4*)&e_b[k * 4] = o;
        } else {
            int k = i - N1 - N2 - N3;
            us4 z = { 0, 0, 0, 0 };
            *(us4*)&hbuf[k * 4] = z;
        }
    }
}

// Zero the barrier counter. Runs between k_gemm_xg (last reader of e_b, whose
// first bytes the counter overlays) and k_recur.
__global__ void k_zero_bar(unsigned int* bar) { bar[threadIdx.x] = 0u; }

// ---------------------------------------------------------------------------
// Phase A: xg[m][g] = E[m][:] . Wih[g][:] + bih[g]   (bt-GEMM, m97 structure)
// grid (64, 24), 256 threads, 128x128 tile, BK=32.
// ---------------------------------------------------------------------------
__global__ __launch_bounds__(256) void k_gemm_xg(const ushort_t* __restrict__ A,
                                                 const ushort_t* __restrict__ Bm,
                                                 const float* __restrict__ bih,
                                                 ushort_t* __restrict__ xg) {
    __shared__ __align__(16) ushort_t Al[128 * 32];
    __shared__ __align__(16) ushort_t Bl[128 * 32];
    const int tid = threadIdx.x;
    const int m0 = blockIdx.x * 128, n0 = blockIdx.y * 128;
    const int wid = tid >> 6, lane = tid & 63;
    const int wm = wid & 1, wn = wid >> 1;
    const int lr = lane & 15, lq = lane >> 4;
    floatx4 acc[4][4] = {};
    for (int kb = 0; kb < KA / 32; ++kb) {
        const int k0 = kb * 32;
        #pragma unroll
        for (int j = 0; j < 2; ++j) {
            int c = j * 256 + tid;          // 512 16B chunks per matrix
            int row = c >> 2, k8 = c & 3;
            gload_lds16(A  + (size_t)(m0 + row) * KA + k0 + k8 * 8, &Al[c * 8]);
            gload_lds16(Bm + (size_t)(n0 + row) * KA + k0 + k8 * 8, &Bl[c * 8]);
        }
        __syncthreads();
        bf16x8 af[4], bf[4];
        #pragma unroll
        for (int i = 0; i < 4; ++i) af[i] = *(const bf16x8*)&Al[(wm * 64 + i * 16 + lr) * 32 + lq * 8];
        #pragma unroll
        for (int j = 0; j < 4; ++j) bf[j] = *(const bf16x8*)&Bl[(wn * 64 + j * 16 + lr) * 32 + lq * 8];
        #pragma unroll
        for (int i = 0; i < 4; ++i)
            #pragma unroll
            for (int j = 0; j < 4; ++j)
                acc[i][j] = mfma16(af[i], bf[j], acc[i][j]);
        __syncthreads();
    }
    #pragma unroll
    for (int i = 0; i < 4; ++i) {
        int grow = m0 + wm * 64 + i * 16 + lq * 4;
        #pragma unroll
        for (int j = 0; j < 4; ++j) {
            int gcol = n0 + wn * 64 + j * 16 + lr;
            float bv = bih[gcol];
            #pragma unroll
            for (int r = 0; r < 4; ++r)
                xg[(size_t)(grow + r) * G3 + gcol] = f2bf(acc[i][j][r] + bv);
        }
    }
}

// ---------------------------------------------------------------------------
// Recurrence: PLAIN-launched persistent kernel, 256 WGs x 256 thr (all
// co-resident by capacity). Body is byte-identical to the R2-proven version:
// WG = (slab s: 16 h-cols, quarter q: 32 batch rows); w_hh fragments in VGPRs
// (K split 4-ways across waves); h staged per step into swizzled LDS with
// normal loads; full-grid fenced barrier per step; h double-buffered.
// ---------------------------------------------------------------------------
__global__ __launch_bounds__(256) void k_recur(const ushort_t* __restrict__ xg,
                                               const ushort_t* __restrict__ whh,
                                               const float* __restrict__ bhh,
                                               const int*   __restrict__ slen,
                                               ushort_t* __restrict__ hbuf,
                                               float* __restrict__ finalbuf,
                                               unsigned int* __restrict__ bar) {
    __shared__ __align__(16) unsigned char smem[65536];
    ushort_t* Al = (ushort_t*)smem;          // 32 x 1024 bf16, xor-swizzled
    float*    P  = (float*)smem;             // reused: 4x2x3x16x16 f32 partials
    const int tid = threadIdx.x, lane = tid & 63, kq = tid >> 6;
    const int s = blockIdx.x >> 2, q = blockIdx.x & 3;
    const int lr = lane & 15, lq = lane >> 4;

    // --- load this wave's w_hh fragments into registers (static across steps)
    bf16x8 Bf[3][8];
    #pragma unroll
    for (int nt = 0; nt < 3; ++nt) {
        const ushort_t* wrow = whh + (size_t)(nt * H_SZ + s * 16 + lr) * H_SZ;
        #pragma unroll
        for (int i = 0; i < 8; ++i)
            Bf[nt][i] = *(const bf16x8*)(wrow + kq * 256 + i * 32 + lq * 8);
    }

    for (int t = 0; t < 64; ++t) {
        const ushort_t* hrd = hbuf + (t & 1) * (B_SZ * H_SZ);
        ushort_t*       hwr = hbuf + ((t + 1) & 1) * (B_SZ * H_SZ);
        // --- stage h rows [32q, 32q+32) x 1024 into LDS (xor swizzle on 16B chunks)
        #pragma unroll
        for (int it = 0; it < 16; ++it) {
            int c = it * 256 + tid;           // 0..4095
            int row = c >> 7, cc = c & 127;
            us8 v = *(const us8*)(hrd + (size_t)(32 * q + row) * H_SZ + cc * 8);
            *(us8*)&Al[(row * 128 + (cc ^ (row & 7))) * 8] = v;
        }
        __syncthreads();
        // --- GEMM: this wave handles K slice [256*kq, 256*kq+256)
        floatx4 acc[2][3] = {};
        #pragma unroll
        for (int i = 0; i < 8; ++i) {
            int cb = 32 * kq + 4 * i + lq;    // 16B chunk index within a row
            int r0 = lr, r1 = 16 + lr;
            bf16x8 a0 = *(const bf16x8*)&Al[(r0 * 128 + (cb ^ (r0 & 7))) * 8];
            bf16x8 a1 = *(const bf16x8*)&Al[(r1 * 128 + (cb ^ (r1 & 7))) * 8];
            #pragma unroll
            for (int nt = 0; nt < 3; ++nt) {
                acc[0][nt] = mfma16(a0, Bf[nt][i], acc[0][nt]);
                acc[1][nt] = mfma16(a1, Bf[nt][i], acc[1][nt]);
            }
        }
        // --- read h_old for this thread's two gate elements from LDS (still valid)
        float holdv[2];
        #pragma unroll
        for (int e2 = 0; e2 < 2; ++e2) {
            int e  = e2 * 256 + tid;
            int bl = e >> 4, j = e & 15;
            int cc = s * 2 + (j >> 3);
            holdv[e2] = bf2f(Al[(bl * 128 + (cc ^ (bl & 7))) * 8 + (j & 7)]);
        }
        __syncthreads();                      // done with Al; reuse as P
        // --- write K-partials: P[kq][mt][nt][rowInTile][col]
        #pragma unroll
        for (int mt = 0; mt < 2; ++mt)
            #pragma unroll
            for (int nt = 0; nt < 3; ++nt)
                #pragma unroll
                for (int r = 0; r < 4; ++r)
                    P[(kq * 6 + mt * 3 + nt) * 256 + (lq * 4 + r) * 16 + lr] = acc[mt][nt][r];
        __syncthreads();
        // --- gate phase: 512 h elements, 2 per thread
        #pragma unroll
        for (int e2 = 0; e2 < 2; ++e2) {
            int e  = e2 * 256 + tid;          // 0..511
            int bl = e >> 4, j = e & 15;
            int mt = bl >> 4, ri = bl & 15;
            float hg[3];
            #pragma unroll
            for (int nt = 0; nt < 3; ++nt) {
                int base = (mt * 3 + nt) * 256 + ri * 16 + j;
                hg[nt] = P[base] + P[base + 6 * 256] + P[base + 12 * 256] + P[base + 18 * 256];
            }
            int bg  = 32 * q + bl;
            int col = s * 16 + j;
            size_t xb = (size_t)(bg * T_SZ + t) * G3 + col;
            float xr = bf2f(xg[xb]);
            float xz = bf2f(xg[xb + 1024]);
            float xn = bf2f(xg[xb + 2048]);
            float rr = fsigmoid(xr + hg[0] + bhh[col]);
            float zz = fsigmoid(xz + hg[1] + bhh[1024 + col]);
            float nn = ftanh(xn + rr * (hg[2] + bhh[2048 + col]));
            float hnew = (1.0f - zz) * nn + zz * holdv[e2];
            hwr[(size_t)bg * H_SZ + col] = f2bf(hnew);
            if (slen[bg] - 1 == t) finalbuf[(size_t)bg * H_SZ + col] = hnew;
        }
        if (t != 63) grid_barrier(bar, (unsigned int)(NWG * (t + 1)));
    }
}

// ---------------------------------------------------------------------------
// Final L2-normalize per batch row.
// ---------------------------------------------------------------------------
__global__ __launch_bounds__(256) void k_norm(const float* __restrict__ finalbuf,
                                              float* __restrict__ out) {
    const int b = blockIdx.x, tid = threadIdx.x;
    const float4 v = ((const float4*)(finalbuf + (size_t)b * H_SZ))[tid];
    float ss = v.x * v.x + v.y * v.y + v.z * v.z + v.w * v.w;
    #pragma unroll
    for (int off = 32; off > 0; off >>= 1) ss += __shfl_down(ss, off);
    __shared__ float red[4];
    const int wid = tid >> 6, lane = tid & 63;
    if (lane == 0) red[wid] = ss;
    __syncthreads();
    const float total = red[0] + red[1] + red[2] + red[3];
    const float inv = 1.0f / sqrtf(total);
    float4 o;
    o.x = v.x * inv; o.y = v.y * inv; o.z = v.z * inv; o.w = v.w * inv;
    ((float4*)(out + (size_t)b * H_SZ))[tid] = o;
}

extern "C" void kernel_launch(void* const* d_in, const int* in_sizes, int n_in,
                              void* d_out, int out_size, void* d_ws, size_t ws_size,
                              hipStream_t stream) {
    const int*   sent = (const int*)d_in[0];
    const int*   slen = (const int*)d_in[1];
    const float* emb  = (const float*)d_in[2];
    const float* wih  = (const float*)d_in[3];
    const float* whh  = (const float*)d_in[4];
    const float* bih  = (const float*)d_in[5];
    const float* bhh  = (const float*)d_in[6];
    float* out = (float*)d_out;
    char* ws = (char*)d_ws;

    // workspace layout (bytes)
    ushort_t* e_b      = (ushort_t*)(ws);                 //  8,388,608  (8192x512 bf16)
    ushort_t* wih_b    = (ushort_t*)(ws + 8388608);       //  3,145,728
    ushort_t* whh_b    = (ushort_t*)(ws + 11534336);      //  6,291,456
    ushort_t* xg       = (ushort_t*)(ws + 17825792);      // 50,331,648  (8192x3072 bf16)
    ushort_t* hbuf     = (ushort_t*)(ws + 68157440);      //    524,288  (2 x 128x1024 bf16)
    float*    finalbuf = (float*)   (ws + 68681728);      //    524,288  (128x1024 f32)
    // barrier counter overlays e_b[0..255] — e_b is dead after k_gemm_xg
    unsigned int* bar  = (unsigned int*)(ws);

    hipLaunchKernelGGL(k_prep, dim3(1024), dim3(256), 0, stream,
                       wih, whh, emb, sent, wih_b, whh_b, e_b, hbuf);
    hipLaunchKernelGGL(k_gemm_xg, dim3(64, 24), dim3(256), 0, stream,
                       e_b, wih_b, bih, xg);
    hipLaunchKernelGGL(k_zero_bar, dim3(1), dim3(256), 0, stream, bar);
    // PLAIN launch (not cooperative): all 256 WGs are co-resident by capacity
    // (64 KB LDS -> <=2 blocks/CU -> grid 256 <= 512 resident), so the custom
    // spin barrier is safe. This removes the silently-failing
    // hipLaunchCooperativeKernel path suspected in rounds 3-5.
    hipLaunchKernelGGL(k_recur, dim3(256), dim3(256), 0, stream,
                       xg, whh_b, bhh, slen, hbuf, finalbuf, bar);
    hipLaunchKernelGGL(k_norm, dim3(128), dim3(256), 0, stream, finalbuf, out);
}

// Round 7
// 871.750 us; speedup vs baseline: 4.3563x; 3.5092x over previous
//
#include <hip/hip_runtime.h>
#include <hip/hip_bf16.h>

typedef unsigned short ushort_t;
typedef __bf16 bf16x8 __attribute__((ext_vector_type(8)));
typedef float floatx4 __attribute__((ext_vector_type(4)));
typedef unsigned short us8 __attribute__((ext_vector_type(8)));
typedef unsigned short us4 __attribute__((ext_vector_type(4)));

#define B_SZ   128
#define T_SZ   64
#define E_SZ   512
#define H_SZ   1024
#define G3     3072          // 3*H
#define MA     8192          // B*T
#define KA     512           // E
#define NWGQ   64            // WGs per batch-quarter barrier

__device__ __forceinline__ float bf2f(unsigned short u) {
    return __uint_as_float(((unsigned int)u) << 16);
}
__device__ __forceinline__ unsigned short f2bf(float f) {
    unsigned int u = __float_as_uint(f);
    u += 0x7fffu + ((u >> 16) & 1u);       // round-to-nearest-even
    return (unsigned short)(u >> 16);
}
__device__ __forceinline__ float fsigmoid(float x) { return 1.0f / (1.0f + __expf(-x)); }
__device__ __forceinline__ float ftanh(float x) {
    float ax = fabsf(x);
    float e  = __expf(2.0f * ax);
    float t  = 1.0f - 2.0f / (e + 1.0f);   // graceful at overflow: -> 1
    return copysignf(t, x);
}
__device__ __forceinline__ void gload_lds16(const ushort_t* g, ushort_t* l) {
    __builtin_amdgcn_global_load_lds((const __attribute__((address_space(1))) unsigned int*)g,
                                     (__attribute__((address_space(3))) unsigned int*)l, 16, 0, 0);
}
__device__ __forceinline__ floatx4 mfma16(bf16x8 a, bf16x8 b, floatx4 c) {
    return __builtin_amdgcn_mfma_f32_16x16x32_bf16(a, b, c, 0, 0, 0);
}

// Fence-free quarter barrier (runs under PLAIN launch; all 256 WGs
// co-resident by capacity). NO __threadfence anywhere in the step loop:
//  - All cross-WG h data is written via relaxed SYSTEM-scope atomic stores
//    (sc0 sc1, write-through to the MALL coherence point) and read via
//    relaxed SYSTEM-scope atomic loads (sc0 sc1, L1/L2-bypassing, sourced
//    from the MALL). No buffer_wbl2 / buffer_inv tag-walks — that fixed
//    per-fence cost is the theory for R2/R6's 46 us/step.
//  - __syncthreads' implicit s_waitcnt vmcnt(0) drains each wave's h
//    stores before thread 0 publishes arrival at the MALL counter.
//    UNTESTED ASSUMPTION (this round's experiment): vmcnt-retirement of a
//    sc0sc1 store implies arrival at the MALL. If false -> flaky absmax,
//    and round 8 switches to returning atomic swaps for h.
//  - Barrier spans only the 64 WGs of one batch quarter: quarter q's h rows
//    are written/read exclusively by WGs with (blockIdx.x & 3) == q, so the
//    four recurrences are independent (pure index math).
__device__ __forceinline__ void quarter_barrier(unsigned int* bar, unsigned int target) {
    asm volatile("s_waitcnt vmcnt(0)" ::: "memory");   // belt & braces drain
    __syncthreads();
    if (threadIdx.x == 0) {
        __hip_atomic_fetch_add(bar, 1u, __ATOMIC_RELAXED, __HIP_MEMORY_SCOPE_SYSTEM);
        while (__hip_atomic_load(bar, __ATOMIC_RELAXED, __HIP_MEMORY_SCOPE_SYSTEM) < target)
            __builtin_amdgcn_s_sleep(1);
    }
    __syncthreads();
}

// ---------------------------------------------------------------------------
// Prep: f32->bf16 weight conversion, embedding gather+convert, zero h0 buffer.
// ---------------------------------------------------------------------------
__global__ __launch_bounds__(256) void k_prep(const float* __restrict__ wih,
                                              const float* __restrict__ whh,
                                              const float* __restrict__ emb,
                                              const int*   __restrict__ sent,
                                              ushort_t* __restrict__ wih_b,
                                              ushort_t* __restrict__ whh_b,
                                              ushort_t* __restrict__ e_b,
                                              ushort_t* __restrict__ hbuf) {
    const int N1 = G3 * E_SZ / 4;        // 393216   w_ih quads
    const int N2 = G3 * H_SZ / 4;        // 786432   w_hh quads
    const int N3 = MA * E_SZ / 4;        // 1048576  gathered emb quads
    const int N4 = B_SZ * H_SZ / 4;      // 32768    h0 quads (buffer 0 only)
    const int total = N1 + N2 + N3 + N4;
    for (int i = blockIdx.x * blockDim.x + threadIdx.x; i < total;
         i += gridDim.x * blockDim.x) {
        if (i < N1) {
            float4 v = ((const float4*)wih)[i];
            us4 o = { f2bf(v.x), f2bf(v.y), f2bf(v.z), f2bf(v.w) };
            *(us4*)&wih_b[i * 4] = o;
        } else if (i < N1 + N2) {
            int k = i - N1;
            float4 v = ((const float4*)whh)[k];
            us4 o = { f2bf(v.x), f2bf(v.y), f2bf(v.z), f2bf(v.w) };
            *(us4*)&whh_b[k * 4] = o;
        } else if (i < N1 + N2 + N3) {
            int k = i - N1 - N2;
            int m  = k >> 7;              // row in [0, 8192)
            int e4 = k & 127;             // float4 index within row
            float4 v = ((const float4*)(emb + (size_t)sent[m] * E_SZ))[e4];
            us4 o = { f2bf(v.x), f2bf(v.y), f2bf(v.z), f2bf(v.w) };
            *(us4*)&e_b[k * 4] = o;
        } else {
            int k = i - N1 - N2 - N3;
            us4 z = { 0, 0, 0, 0 };
            *(us4*)&hbuf[k * 4] = z;
        }
    }
}

// Zero the barrier counters (4 quarters at 64-uint stride). Runs between
// k_gemm_xg (last reader of e_b, which the counters overlay) and k_recur.
__global__ void k_zero_bar(unsigned int* bar) { bar[threadIdx.x] = 0u; }

// ---------------------------------------------------------------------------
// Phase A: xg[m][g] = E[m][:] . Wih[g][:] + bih[g]   (bt-GEMM, m97 structure)
// grid (64, 24), 256 threads, 128x128 tile, BK=32.
// ---------------------------------------------------------------------------
__global__ __launch_bounds__(256) void k_gemm_xg(const ushort_t* __restrict__ A,
                                                 const ushort_t* __restrict__ Bm,
                                                 const float* __restrict__ bih,
                                                 ushort_t* __restrict__ xg) {
    __shared__ __align__(16) ushort_t Al[128 * 32];
    __shared__ __align__(16) ushort_t Bl[128 * 32];
    const int tid = threadIdx.x;
    const int m0 = blockIdx.x * 128, n0 = blockIdx.y * 128;
    const int wid = tid >> 6, lane = tid & 63;
    const int wm = wid & 1, wn = wid >> 1;
    const int lr = lane & 15, lq = lane >> 4;
    floatx4 acc[4][4] = {};
    for (int kb = 0; kb < KA / 32; ++kb) {
        const int k0 = kb * 32;
        #pragma unroll
        for (int j = 0; j < 2; ++j) {
            int c = j * 256 + tid;          // 512 16B chunks per matrix
            int row = c >> 2, k8 = c & 3;
            gload_lds16(A  + (size_t)(m0 + row) * KA + k0 + k8 * 8, &Al[c * 8]);
            gload_lds16(Bm + (size_t)(n0 + row) * KA + k0 + k8 * 8, &Bl[c * 8]);
        }
        __syncthreads();
        bf16x8 af[4], bf[4];
        #pragma unroll
        for (int i = 0; i < 4; ++i) af[i] = *(const bf16x8*)&Al[(wm * 64 + i * 16 + lr) * 32 + lq * 8];
        #pragma unroll
        for (int j = 0; j < 4; ++j) bf[j] = *(const bf16x8*)&Bl[(wn * 64 + j * 16 + lr) * 32 + lq * 8];
        #pragma unroll
        for (int i = 0; i < 4; ++i)
            #pragma unroll
            for (int j = 0; j < 4; ++j)
                acc[i][j] = mfma16(af[i], bf[j], acc[i][j]);
        __syncthreads();
    }
    #pragma unroll
    for (int i = 0; i < 4; ++i) {
        int grow = m0 + wm * 64 + i * 16 + lq * 4;
        #pragma unroll
        for (int j = 0; j < 4; ++j) {
            int gcol = n0 + wn * 64 + j * 16 + lr;
            float bv = bih[gcol];
            #pragma unroll
            for (int r = 0; r < 4; ++r)
                xg[(size_t)(grow + r) * G3 + gcol] = f2bf(acc[i][j][r] + bv);
        }
    }
}

// ---------------------------------------------------------------------------
// Recurrence: PLAIN-launched persistent kernel, 256 WGs x 256 thr (all
// co-resident by capacity). WG = (slab s: 16 h-cols, quarter q: 32 batch
// rows). w_hh fragments in VGPRs (K split 4-ways across waves); h staged per
// step into swizzled LDS via SYSTEM-scope (MALL) loads; h written back via
// SYSTEM-scope write-through stores; fence-free per-quarter barrier.
// ---------------------------------------------------------------------------
__global__ __launch_bounds__(256) void k_recur(const ushort_t* __restrict__ xg,
                                               const ushort_t* __restrict__ whh,
                                               const float* __restrict__ bhh,
                                               const int*   __restrict__ slen,
                                               ushort_t* __restrict__ hbuf,
                                               float* __restrict__ finalbuf,
                                               unsigned int* __restrict__ bar) {
    __shared__ __align__(16) unsigned char smem[65536];
    ushort_t* Al = (ushort_t*)smem;          // 32 x 1024 bf16, xor-swizzled
    float*    P  = (float*)smem;             // reused: 4x2x3x16x16 f32 partials
    const int tid = threadIdx.x, lane = tid & 63, kq = tid >> 6;
    const int s = blockIdx.x >> 2, q = blockIdx.x & 3;
    const int lr = lane & 15, lq = lane >> 4;
    unsigned int* qbar = bar + q * 64;       // 256B-separated per-quarter counters

    // --- load this wave's w_hh fragments into registers (static across steps)
    bf16x8 Bf[3][8];
    #pragma unroll
    for (int nt = 0; nt < 3; ++nt) {
        const ushort_t* wrow = whh + (size_t)(nt * H_SZ + s * 16 + lr) * H_SZ;
        #pragma unroll
        for (int i = 0; i < 8; ++i)
            Bf[nt][i] = *(const bf16x8*)(wrow + kq * 256 + i * 32 + lq * 8);
    }

    for (int t = 0; t < 64; ++t) {
        const ushort_t* hrd = hbuf + (t & 1) * (B_SZ * H_SZ);
        ushort_t*       hwr = hbuf + ((t + 1) & 1) * (B_SZ * H_SZ);
        // --- stage h rows [32q, 32q+32) x 1024 into LDS (xor swizzle on 16B
        //     chunks). SYSTEM-scope relaxed atomic loads = global_load_dwordx2
        //     sc0 sc1 (L1/L2 bypass, MALL-sourced), compiler-generated and
        //     vmcnt-tracked — no hand asm on the data path.
        #pragma unroll
        for (int it = 0; it < 32; ++it) {
            int c = it * 256 + tid;           // 0..8191  (8B chunks)
            int row = c >> 8, cc8 = c & 255;
            unsigned long long v = __hip_atomic_load(
                (const unsigned long long*)(hrd + (size_t)(32 * q + row) * H_SZ + cc8 * 4),
                __ATOMIC_RELAXED, __HIP_MEMORY_SCOPE_SYSTEM);
            int cc16 = cc8 >> 1, half = cc8 & 1;
            *(unsigned long long*)&Al[(row * 128 + (cc16 ^ (row & 7))) * 8 + half * 4] = v;
        }
        __syncthreads();
        // --- GEMM: this wave handles K slice [256*kq, 256*kq+256)
        floatx4 acc[2][3] = {};
        #pragma unroll
        for (int i = 0; i < 8; ++i) {
            int cb = 32 * kq + 4 * i + lq;    // 16B chunk index within a row
            int r0 = lr, r1 = 16 + lr;
            bf16x8 a0 = *(const bf16x8*)&Al[(r0 * 128 + (cb ^ (r0 & 7))) * 8];
            bf16x8 a1 = *(const bf16x8*)&Al[(r1 * 128 + (cb ^ (r1 & 7))) * 8];
            #pragma unroll
            for (int nt = 0; nt < 3; ++nt) {
                acc[0][nt] = mfma16(a0, Bf[nt][i], acc[0][nt]);
                acc[1][nt] = mfma16(a1, Bf[nt][i], acc[1][nt]);
            }
        }
        // --- read h_old for this thread's two gate elements from LDS (still valid)
        float holdv[2];
        #pragma unroll
        for (int e2 = 0; e2 < 2; ++e2) {
            int e  = e2 * 256 + tid;
            int bl = e >> 4, j = e & 15;
            int cc = s * 2 + (j >> 3);
            holdv[e2] = bf2f(Al[(bl * 128 + (cc ^ (bl & 7))) * 8 + (j & 7)]);
        }
        __syncthreads();                      // done with Al; reuse as P
        // --- write K-partials: P[kq][mt][nt][rowInTile][col]
        #pragma unroll
        for (int mt = 0; mt < 2; ++mt)
            #pragma unroll
            for (int nt = 0; nt < 3; ++nt)
                #pragma unroll
                for (int r = 0; r < 4; ++r)
                    P[(kq * 6 + mt * 3 + nt) * 256 + (lq * 4 + r) * 16 + lr] = acc[mt][nt][r];
        __syncthreads();
        // --- gate phase: 512 h elements, 2 per thread
        #pragma unroll
        for (int e2 = 0; e2 < 2; ++e2) {
            int e  = e2 * 256 + tid;          // 0..511
            int bl = e >> 4, j = e & 15;
            int mt = bl >> 4, ri = bl & 15;
            float hg[3];
            #pragma unroll
            for (int nt = 0; nt < 3; ++nt) {
                int base = (mt * 3 + nt) * 256 + ri * 16 + j;
                hg[nt] = P[base] + P[base + 6 * 256] + P[base + 12 * 256] + P[base + 18 * 256];
            }
            int bg  = 32 * q + bl;
            int col = s * 16 + j;
            size_t xb = (size_t)(bg * T_SZ + t) * G3 + col;
            float xr = bf2f(xg[xb]);
            float xz = bf2f(xg[xb + 1024]);
            float xn = bf2f(xg[xb + 2048]);
            float rr = fsigmoid(xr + hg[0] + bhh[col]);
            float zz = fsigmoid(xz + hg[1] + bhh[1024 + col]);
            float nn = ftanh(xn + rr * (hg[2] + bhh[2048 + col]));
            float hnew = (1.0f - zz) * nn + zz * holdv[e2];
            // SYSTEM-scope relaxed store: global_store_short sc0 sc1 —
            // write-through to the MALL, no L2 dirtying, no fence needed.
            __hip_atomic_store(&hwr[(size_t)bg * H_SZ + col], f2bf(hnew),
                               __ATOMIC_RELAXED, __HIP_MEMORY_SCOPE_SYSTEM);
            if (slen[bg] - 1 == t) finalbuf[(size_t)bg * H_SZ + col] = hnew;
        }
        if (t != 63) quarter_barrier(qbar, (unsigned int)(NWGQ * (t + 1)));
    }
}

// ---------------------------------------------------------------------------
// Final L2-normalize per batch row.
// ---------------------------------------------------------------------------
__global__ __launch_bounds__(256) void k_norm(const float* __restrict__ finalbuf,
                                              float* __restrict__ out) {
    const int b = blockIdx.x, tid = threadIdx.x;
    const float4 v = ((const float4*)(finalbuf + (size_t)b * H_SZ))[tid];
    float ss = v.x * v.x + v.y * v.y + v.z * v.z + v.w * v.w;
    #pragma unroll
    for (int off = 32; off > 0; off >>= 1) ss += __shfl_down(ss, off);
    __shared__ float red[4];
    const int wid = tid >> 6, lane = tid & 63;
    if (lane == 0) red[wid] = ss;
    __syncthreads();
    const float total = red[0] + red[1] + red[2] + red[3];
    const float inv = 1.0f / sqrtf(total);
    float4 o;
    o.x = v.x * inv; o.y = v.y * inv; o.z = v.z * inv; o.w = v.w * inv;
    ((float4*)(out + (size_t)b * H_SZ))[tid] = o;
}

extern "C" void kernel_launch(void* const* d_in, const int* in_sizes, int n_in,
                              void* d_out, int out_size, void* d_ws, size_t ws_size,
                              hipStream_t stream) {
    const int*   sent = (const int*)d_in[0];
    const int*   slen = (const int*)d_in[1];
    const float* emb  = (const float*)d_in[2];
    const float* wih  = (const float*)d_in[3];
    const float* whh  = (const float*)d_in[4];
    const float* bih  = (const float*)d_in[5];
    const float* bhh  = (const float*)d_in[6];
    float* out = (float*)d_out;
    char* ws = (char*)d_ws;

    // workspace layout (bytes)
    ushort_t* e_b      = (ushort_t*)(ws);                 //  8,388,608  (8192x512 bf16)
    ushort_t* wih_b    = (ushort_t*)(ws + 8388608);       //  3,145,728
    ushort_t* whh_b    = (ushort_t*)(ws + 11534336);      //  6,291,456
    ushort_t* xg       = (ushort_t*)(ws + 17825792);      // 50,331,648  (8192x3072 bf16)
    ushort_t* hbuf     = (ushort_t*)(ws + 68157440);      //    524,288  (2 x 128x1024 bf16)
    float*    finalbuf = (float*)   (ws + 68681728);      //    524,288  (128x1024 f32)
    // barrier counters overlay e_b[0..255] — e_b is dead after k_gemm_xg
    unsigned int* bar  = (unsigned int*)(ws);

    hipLaunchKernelGGL(k_prep, dim3(1024), dim3(256), 0, stream,
                       wih, whh, emb, sent, wih_b, whh_b, e_b, hbuf);
    hipLaunchKernelGGL(k_gemm_xg, dim3(64, 24), dim3(256), 0, stream,
                       e_b, wih_b, bih, xg);
    hipLaunchKernelGGL(k_zero_bar, dim3(1), dim3(256), 0, stream, bar);
    // PLAIN launch (R6-verified): all 256 WGs co-resident by capacity, so the
    // custom spin barrier is safe without cooperative launch.
    hipLaunchKernelGGL(k_recur, dim3(256), dim3(256), 0, stream,
                       xg, whh_b, bhh, slen, hbuf, finalbuf, bar);
    hipLaunchKernelGGL(k_norm, dim3(128), dim3(256), 0, stream, finalbuf, out);
}

// Round 8
// 547.571 us; speedup vs baseline: 6.9354x; 1.5920x over previous
//
#include <hip/hip_runtime.h>
#include <hip/hip_bf16.h>

typedef unsigned short ushort_t;
typedef __bf16 bf16x8 __attribute__((ext_vector_type(8)));
typedef float floatx4 __attribute__((ext_vector_type(4)));
typedef unsigned short us8 __attribute__((ext_vector_type(8)));
typedef unsigned short us4 __attribute__((ext_vector_type(4)));

#define B_SZ   128
#define T_SZ   64
#define E_SZ   512
#define H_SZ   1024
#define G3     3072          // 3*H
#define MA     8192          // B*T
#define KA     512           // E

__device__ __forceinline__ float bf2f(unsigned short u) {
    return __uint_as_float(((unsigned int)u) << 16);
}
__device__ __forceinline__ unsigned short f2bf(float f) {
    unsigned int u = __float_as_uint(f);
    u += 0x7fffu + ((u >> 16) & 1u);       // round-to-nearest-even
    return (unsigned short)(u >> 16);
}
__device__ __forceinline__ float fsigmoid(float x) { return 1.0f / (1.0f + __expf(-x)); }
__device__ __forceinline__ float ftanh(float x) {
    float ax = fabsf(x);
    float e  = __expf(2.0f * ax);
    float t  = 1.0f - 2.0f / (e + 1.0f);   // graceful at overflow: -> 1
    return copysignf(t, x);
}
__device__ __forceinline__ void gload_lds16(const ushort_t* g, ushort_t* l) {
    __builtin_amdgcn_global_load_lds((const __attribute__((address_space(1))) unsigned int*)g,
                                     (__attribute__((address_space(3))) unsigned int*)l, 16, 0, 0);
}
__device__ __forceinline__ floatx4 mfma16(bf16x8 a, bf16x8 b, floatx4 c) {
    return __builtin_amdgcn_mfma_f32_16x16x32_bf16(a, b, c, 0, 0, 0);
}

// ---------------------------------------------------------------------------
// Prep: f32->bf16 weight conversion, embedding gather+convert, zero h0 buffer.
// ---------------------------------------------------------------------------
__global__ __launch_bounds__(256) void k_prep(const float* __restrict__ wih,
                                              const float* __restrict__ whh,
                                              const float* __restrict__ emb,
                                              const int*   __restrict__ sent,
                                              ushort_t* __restrict__ wih_b,
                                              ushort_t* __restrict__ whh_b,
                                              ushort_t* __restrict__ e_b,
                                              ushort_t* __restrict__ hbuf) {
    const int N1 = G3 * E_SZ / 4;        // 393216   w_ih quads
    const int N2 = G3 * H_SZ / 4;        // 786432   w_hh quads
    const int N3 = MA * E_SZ / 4;        // 1048576  gathered emb quads
    const int N4 = B_SZ * H_SZ / 4;      // 32768    h0 quads (buffer 0 only)
    const int total = N1 + N2 + N3 + N4;
    for (int i = blockIdx.x * blockDim.x + threadIdx.x; i < total;
         i += gridDim.x * blockDim.x) {
        if (i < N1) {
            float4 v = ((const float4*)wih)[i];
            us4 o = { f2bf(v.x), f2bf(v.y), f2bf(v.z), f2bf(v.w) };
            *(us4*)&wih_b[i * 4] = o;
        } else if (i < N1 + N2) {
            int k = i - N1;
            float4 v = ((const float4*)whh)[k];
            us4 o = { f2bf(v.x), f2bf(v.y), f2bf(v.z), f2bf(v.w) };
            *(us4*)&whh_b[k * 4] = o;
        } else if (i < N1 + N2 + N3) {
            int k = i - N1 - N2;
            int m  = k >> 7;              // row in [0, 8192)
            int e4 = k & 127;             // float4 index within row
            float4 v = ((const float4*)(emb + (size_t)sent[m] * E_SZ))[e4];
            us4 o = { f2bf(v.x), f2bf(v.y), f2bf(v.z), f2bf(v.w) };
            *(us4*)&e_b[k * 4] = o;
        } else {
            int k = i - N1 - N2 - N3;
            us4 z = { 0, 0, 0, 0 };
            *(us4*)&hbuf[k * 4] = z;
        }
    }
}

// Zero the 256 per-WG barrier flags (128B-spaced; 8192 uints = 32 KB).
// Runs between k_gemm_xg (last reader of e_b, which the flags overlay) and
// k_recur. Kernel-end writeback makes the zeros visible at the MALL.
__global__ void k_zero_bar(unsigned int* bar) {
    bar[blockIdx.x * 256 + threadIdx.x] = 0u;
}

// ---------------------------------------------------------------------------
// Phase A: xg[m][g] = E[m][:] . Wih[g][:] + bih[g]   (bt-GEMM, m97 structure)
// grid (64, 24), 256 threads, 128x128 tile, BK=32.
// ---------------------------------------------------------------------------
__global__ __launch_bounds__(256) void k_gemm_xg(const ushort_t* __restrict__ A,
                                                 const ushort_t* __restrict__ Bm,
                                                 const float* __restrict__ bih,
                                                 ushort_t* __restrict__ xg) {
    __shared__ __align__(16) ushort_t Al[128 * 32];
    __shared__ __align__(16) ushort_t Bl[128 * 32];
    const int tid = threadIdx.x;
    const int m0 = blockIdx.x * 128, n0 = blockIdx.y * 128;
    const int wid = tid >> 6, lane = tid & 63;
    const int wm = wid & 1, wn = wid >> 1;
    const int lr = lane & 15, lq = lane >> 4;
    floatx4 acc[4][4] = {};
    for (int kb = 0; kb < KA / 32; ++kb) {
        const int k0 = kb * 32;
        #pragma unroll
        for (int j = 0; j < 2; ++j) {
            int c = j * 256 + tid;          // 512 16B chunks per matrix
            int row = c >> 2, k8 = c & 3;
            gload_lds16(A  + (size_t)(m0 + row) * KA + k0 + k8 * 8, &Al[c * 8]);
            gload_lds16(Bm + (size_t)(n0 + row) * KA + k0 + k8 * 8, &Bl[c * 8]);
        }
        __syncthreads();
        bf16x8 af[4], bf[4];
        #pragma unroll
        for (int i = 0; i < 4; ++i) af[i] = *(const bf16x8*)&Al[(wm * 64 + i * 16 + lr) * 32 + lq * 8];
        #pragma unroll
        for (int j = 0; j < 4; ++j) bf[j] = *(const bf16x8*)&Bl[(wn * 64 + j * 16 + lr) * 32 + lq * 8];
        #pragma unroll
        for (int i = 0; i < 4; ++i)
            #pragma unroll
            for (int j = 0; j < 4; ++j)
                acc[i][j] = mfma16(af[i], bf[j], acc[i][j]);
        __syncthreads();
    }
    #pragma unroll
    for (int i = 0; i < 4; ++i) {
        int grow = m0 + wm * 64 + i * 16 + lq * 4;
        #pragma unroll
        for (int j = 0; j < 4; ++j) {
            int gcol = n0 + wn * 64 + j * 16 + lr;
            float bv = bih[gcol];
            #pragma unroll
            for (int r = 0; r < 4; ++r)
                xg[(size_t)(grow + r) * G3 + gcol] = f2bf(acc[i][j][r] + bv);
        }
    }
}

// ---------------------------------------------------------------------------
// Recurrence: PLAIN-launched persistent kernel, 256 WGs x 256 thr, 1/CU.
// WG w: slab s = w>>2 (16 h-cols), quarter q = w&3 (32 batch rows).
// Changes vs R7 (both attack exposed latency at 1 wave/SIMD):
//  1. NO LDS h-staging: each lane loads its MFMA A-fragments straight from
//     the MALL into registers (fragment partition is exact: lane (lr,lq) of
//     wave kq owns h[32q+16mt+lr][256kq+32i+8lq..+8]); gate-phase h_old is
//     one extra dword/thread. Deletes the 32-iter LDS loop, swizzle math,
//     and one syncthreads. LDS keeps only the 27 KB P-reduction (row stride
//     18 floats to break the 4-way bank conflict of stride 16).
//  2. Flag-store barrier: arrival = one fire-and-forget system-scope dword
//     store to this WG's own 128B-spaced flag (no serialized RMWs on a
//     shared counter); detection = wave 0's lanes 0..63 poll the quarter's
//     64 flags in parallel (one MALL round-trip per iteration, no sleep).
//     Publish safety is R7-proven: per-wave s_waitcnt vmcnt(0) retires the
//     write-through h stores at the MALL, syncthreads collects all waves,
//     then the flag store is issued.
// ---------------------------------------------------------------------------
__global__ __launch_bounds__(256, 1) void k_recur(const ushort_t* __restrict__ xg,
                                                  const ushort_t* __restrict__ whh,
                                                  const float* __restrict__ bhh,
                                                  const int*   __restrict__ slen,
                                                  ushort_t* __restrict__ hbuf,
                                                  float* __restrict__ finalbuf,
                                                  unsigned int* __restrict__ bar) {
    __shared__ float P[24 * 288];            // K-partials, padded stride 18
    const int tid = threadIdx.x, lane = tid & 63, kq = tid >> 6;
    const int w = blockIdx.x, s = w >> 2, q = w & 3;
    const int lr = lane & 15, lq = lane >> 4;
    // gate-phase coords: thread -> (row-in-quarter bl, adjacent col pair j0)
    const int bl = tid >> 3, j0 = (tid & 7) * 2;
    const int bg = 32 * q + bl;              // batch row
    const int gcol = 16 * s + j0;            // h column (even)
    const int mtg = bl >> 4, rig = bl & 15;
    unsigned int* myflag = bar + w * 32;     // 128B-spaced per-WG flag

    // --- hoisted invariants
    const int sl = slen[bg];
    const float2 bR = *(const float2*)&bhh[gcol];
    const float2 bZ = *(const float2*)&bhh[H_SZ + gcol];
    const float2 bN = *(const float2*)&bhh[2 * H_SZ + gcol];

    // --- this wave's w_hh B-fragments (static across steps, 96 VGPRs)
    bf16x8 Bf[3][8];
    #pragma unroll
    for (int nt = 0; nt < 3; ++nt) {
        const ushort_t* wrow = whh + (size_t)(nt * H_SZ + s * 16 + lr) * H_SZ;
        #pragma unroll
        for (int i = 0; i < 8; ++i)
            Bf[nt][i] = *(const bf16x8*)(wrow + kq * 256 + i * 32 + lq * 8);
    }

    union AF { unsigned long long u[2]; bf16x8 v; };

    for (int t = 0; t < 64; ++t) {
        const ushort_t* hrd = hbuf + (t & 1) * (B_SZ * H_SZ);
        ushort_t*       hwr = hbuf + ((t + 1) & 1) * (B_SZ * H_SZ);

        // --- load A-fragments direct from MALL (system-scope relaxed = sc0
        //     sc1, L1/L2-bypassing, vmcnt-tracked), plus h_old + xg for the
        //     gate phase. All issued together; compiler waits as needed.
        AF af[2][8];
        #pragma unroll
        for (int mt = 0; mt < 2; ++mt)
            #pragma unroll
            for (int i = 0; i < 8; ++i) {
                const ushort_t* p = hrd + (size_t)(32 * q + 16 * mt + lr) * H_SZ
                                  + 256 * kq + 32 * i + 8 * lq;
                af[mt][i].u[0] = __hip_atomic_load((const unsigned long long*)p,
                                   __ATOMIC_RELAXED, __HIP_MEMORY_SCOPE_SYSTEM);
                af[mt][i].u[1] = __hip_atomic_load((const unsigned long long*)(p + 4),
                                   __ATOMIC_RELAXED, __HIP_MEMORY_SCOPE_SYSTEM);
            }
        unsigned int holdu = __hip_atomic_load(
            (const unsigned int*)(hrd + (size_t)bg * H_SZ + gcol),
            __ATOMIC_RELAXED, __HIP_MEMORY_SCOPE_SYSTEM);
        const size_t xb = (size_t)(bg * T_SZ + t) * G3 + gcol;
        unsigned int xru = *(const unsigned int*)&xg[xb];
        unsigned int xzu = *(const unsigned int*)&xg[xb + H_SZ];
        unsigned int xnu = *(const unsigned int*)&xg[xb + 2 * H_SZ];

        // --- MFMA: 48 per wave (2 m-tiles x 3 gates x 8 K-chunks)
        floatx4 acc[2][3] = {};
        #pragma unroll
        for (int i = 0; i < 8; ++i)
            #pragma unroll
            for (int nt = 0; nt < 3; ++nt) {
                acc[0][nt] = mfma16(af[0][i].v, Bf[nt][i], acc[0][nt]);
                acc[1][nt] = mfma16(af[1][i].v, Bf[nt][i], acc[1][nt]);
            }

        // --- K-partials to LDS (C-layout: col=lr, row=lq*4+r; stride 18)
        #pragma unroll
        for (int mt = 0; mt < 2; ++mt)
            #pragma unroll
            for (int nt = 0; nt < 3; ++nt)
                #pragma unroll
                for (int r = 0; r < 4; ++r)
                    P[(kq * 6 + mt * 3 + nt) * 288 + (lq * 4 + r) * 18 + lr]
                        = acc[mt][nt][r];
        __syncthreads();

        // --- gate phase: 2 adjacent cols of one row per thread
        {
            float hg0[3], hg1[3];
            #pragma unroll
            for (int nt = 0; nt < 3; ++nt) {
                int base = (mtg * 3 + nt) * 288 + rig * 18 + j0;
                float2 p0 = *(const float2*)&P[base];
                float2 p1 = *(const float2*)&P[base + 6 * 288];
                float2 p2 = *(const float2*)&P[base + 12 * 288];
                float2 p3 = *(const float2*)&P[base + 18 * 288];
                hg0[nt] = p0.x + p1.x + p2.x + p3.x;
                hg1[nt] = p0.y + p1.y + p2.y + p3.y;
            }
            float hold0 = bf2f((unsigned short)(holdu & 0xffff));
            float hold1 = bf2f((unsigned short)(holdu >> 16));
            float r0 = fsigmoid(bf2f((unsigned short)(xru & 0xffff)) + hg0[0] + bR.x);
            float r1 = fsigmoid(bf2f((unsigned short)(xru >> 16))    + hg1[0] + bR.y);
            float z0 = fsigmoid(bf2f((unsigned short)(xzu & 0xffff)) + hg0[1] + bZ.x);
            float z1 = fsigmoid(bf2f((unsigned short)(xzu >> 16))    + hg1[1] + bZ.y);
            float n0 = ftanh(bf2f((unsigned short)(xnu & 0xffff)) + r0 * (hg0[2] + bN.x));
            float n1 = ftanh(bf2f((unsigned short)(xnu >> 16))    + r1 * (hg1[2] + bN.y));
            float h0n = (1.0f - z0) * n0 + z0 * hold0;
            float h1n = (1.0f - z1) * n1 + z1 * hold1;
            unsigned int packed = (unsigned int)f2bf(h0n) | ((unsigned int)f2bf(h1n) << 16);
            __hip_atomic_store((unsigned int*)(hwr + (size_t)bg * H_SZ + gcol), packed,
                               __ATOMIC_RELAXED, __HIP_MEMORY_SCOPE_SYSTEM);
            if (sl - 1 == t) {
                float2 fo; fo.x = h0n; fo.y = h1n;
                *(float2*)(finalbuf + (size_t)bg * H_SZ + gcol) = fo;
            }
        }

        // --- flag-store quarter barrier (skipped on the last step)
        if (t != 63) {
            asm volatile("s_waitcnt vmcnt(0)" ::: "memory");  // per-wave h-store drain
            __syncthreads();                                   // all waves drained
            if (tid == 0)
                __hip_atomic_store(myflag, (unsigned int)(t + 1),
                                   __ATOMIC_RELAXED, __HIP_MEMORY_SCOPE_SYSTEM);
            __atomic_signal_fence(__ATOMIC_SEQ_CST);
            if (tid < 64) {
                const unsigned int* fl = bar + (4 * tid + q) * 32;  // quarter q's flags
                while (__hip_atomic_load(fl, __ATOMIC_RELAXED,
                                         __HIP_MEMORY_SCOPE_SYSTEM) < (unsigned int)(t + 1)) {}
            }
            __syncthreads();
        }
    }
}

// ---------------------------------------------------------------------------
// Final L2-normalize per batch row.
// ---------------------------------------------------------------------------
__global__ __launch_bounds__(256) void k_norm(const float* __restrict__ finalbuf,
                                              float* __restrict__ out) {
    const int b = blockIdx.x, tid = threadIdx.x;
    const float4 v = ((const float4*)(finalbuf + (size_t)b * H_SZ))[tid];
    float ss = v.x * v.x + v.y * v.y + v.z * v.z + v.w * v.w;
    #pragma unroll
    for (int off = 32; off > 0; off >>= 1) ss += __shfl_down(ss, off);
    __shared__ float red[4];
    const int wid = tid >> 6, lane = tid & 63;
    if (lane == 0) red[wid] = ss;
    __syncthreads();
    const float total = red[0] + red[1] + red[2] + red[3];
    const float inv = 1.0f / sqrtf(total);
    float4 o;
    o.x = v.x * inv; o.y = v.y * inv; o.z = v.z * inv; o.w = v.w * inv;
    ((float4*)(out + (size_t)b * H_SZ))[tid] = o;
}

extern "C" void kernel_launch(void* const* d_in, const int* in_sizes, int n_in,
                              void* d_out, int out_size, void* d_ws, size_t ws_size,
                              hipStream_t stream) {
    const int*   sent = (const int*)d_in[0];
    const int*   slen = (const int*)d_in[1];
    const float* emb  = (const float*)d_in[2];
    const float* wih  = (const float*)d_in[3];
    const float* whh  = (const float*)d_in[4];
    const float* bih  = (const float*)d_in[5];
    const float* bhh  = (const float*)d_in[6];
    float* out = (float*)d_out;
    char* ws = (char*)d_ws;

    // workspace layout (bytes)
    ushort_t* e_b      = (ushort_t*)(ws);                 //  8,388,608  (8192x512 bf16)
    ushort_t* wih_b    = (ushort_t*)(ws + 8388608);       //  3,145,728
    ushort_t* whh_b    = (ushort_t*)(ws + 11534336);      //  6,291,456
    ushort_t* xg       = (ushort_t*)(ws + 17825792);      // 50,331,648  (8192x3072 bf16)
    ushort_t* hbuf     = (ushort_t*)(ws + 68157440);      //    524,288  (2 x 128x1024 bf16)
    float*    finalbuf = (float*)   (ws + 68681728);      //    524,288  (128x1024 f32)
    // barrier flags overlay e_b[0..16383] (32 KB) — e_b dead after k_gemm_xg
    unsigned int* bar  = (unsigned int*)(ws);

    hipLaunchKernelGGL(k_prep, dim3(1024), dim3(256), 0, stream,
                       wih, whh, emb, sent, wih_b, whh_b, e_b, hbuf);
    hipLaunchKernelGGL(k_gemm_xg, dim3(64, 24), dim3(256), 0, stream,
                       e_b, wih_b, bih, xg);
    hipLaunchKernelGGL(k_zero_bar, dim3(32), dim3(256), 0, stream, bar);
    // PLAIN launch (R6/R7-verified): 256 WGs co-resident by capacity.
    hipLaunchKernelGGL(k_recur, dim3(256), dim3(256), 0, stream,
                       xg, whh_b, bhh, slen, hbuf, finalbuf, bar);
    hipLaunchKernelGGL(k_norm, dim3(128), dim3(256), 0, stream, finalbuf, out);
}

// Round 9
// 528.545 us; speedup vs baseline: 7.1850x; 1.0360x over previous
//
#include <hip/hip_runtime.h>
#include <hip/hip_bf16.h>

typedef unsigned short ushort_t;
typedef __bf16 bf16x8 __attribute__((ext_vector_type(8)));
typedef float floatx4 __attribute__((ext_vector_type(4)));
typedef unsigned short us8 __attribute__((ext_vector_type(8)));
typedef unsigned short us4 __attribute__((ext_vector_type(4)));

#define B_SZ   128
#define T_SZ   64
#define E_SZ   512
#define H_SZ   1024
#define G3     3072          // 3*H
#define MA     8192          // B*T
#define KA     512           // E

__device__ __forceinline__ float bf2f(unsigned short u) {
    return __uint_as_float(((unsigned int)u) << 16);
}
__device__ __forceinline__ unsigned short f2bf(float f) {
    unsigned int u = __float_as_uint(f);
    u += 0x7fffu + ((u >> 16) & 1u);       // round-to-nearest-even
    return (unsigned short)(u >> 16);
}
__device__ __forceinline__ float fsigmoid(float x) { return 1.0f / (1.0f + __expf(-x)); }
__device__ __forceinline__ float ftanh(float x) {
    float ax = fabsf(x);
    float e  = __expf(2.0f * ax);
    float t  = 1.0f - 2.0f / (e + 1.0f);   // graceful at overflow: -> 1
    return copysignf(t, x);
}
__device__ __forceinline__ void gload_lds16(const ushort_t* g, ushort_t* l) {
    __builtin_amdgcn_global_load_lds((const __attribute__((address_space(1))) unsigned int*)g,
                                     (__attribute__((address_space(3))) unsigned int*)l, 16, 0, 0);
}
__device__ __forceinline__ floatx4 mfma16(bf16x8 a, bf16x8 b, floatx4 c) {
    return __builtin_amdgcn_mfma_f32_16x16x32_bf16(a, b, c, 0, 0, 0);
}

// ---------------------------------------------------------------------------
// Prep: f32->bf16 weight conversion, embedding gather+convert, zero h0 buffer.
// ---------------------------------------------------------------------------
__global__ __launch_bounds__(256) void k_prep(const float* __restrict__ wih,
                                              const float* __restrict__ whh,
                                              const float* __restrict__ emb,
                                              const int*   __restrict__ sent,
                                              ushort_t* __restrict__ wih_b,
                                              ushort_t* __restrict__ whh_b,
                                              ushort_t* __restrict__ e_b,
                                              ushort_t* __restrict__ hbuf) {
    const int N1 = G3 * E_SZ / 4;        // 393216   w_ih quads
    const int N2 = G3 * H_SZ / 4;        // 786432   w_hh quads
    const int N3 = MA * E_SZ / 4;        // 1048576  gathered emb quads
    const int N4 = B_SZ * H_SZ / 4;      // 32768    h0 quads (buffer 0 only)
    const int total = N1 + N2 + N3 + N4;
    for (int i = blockIdx.x * blockDim.x + threadIdx.x; i < total;
         i += gridDim.x * blockDim.x) {
        if (i < N1) {
            float4 v = ((const float4*)wih)[i];
            us4 o = { f2bf(v.x), f2bf(v.y), f2bf(v.z), f2bf(v.w) };
            *(us4*)&wih_b[i * 4] = o;
        } else if (i < N1 + N2) {
            int k = i - N1;
            float4 v = ((const float4*)whh)[k];
            us4 o = { f2bf(v.x), f2bf(v.y), f2bf(v.z), f2bf(v.w) };
            *(us4*)&whh_b[k * 4] = o;
        } else if (i < N1 + N2 + N3) {
            int k = i - N1 - N2;
            int m  = k >> 7;              // row in [0, 8192)
            int e4 = k & 127;             // float4 index within row
            float4 v = ((const float4*)(emb + (size_t)sent[m] * E_SZ))[e4];
            us4 o = { f2bf(v.x), f2bf(v.y), f2bf(v.z), f2bf(v.w) };
            *(us4*)&e_b[k * 4] = o;
        } else {
            int k = i - N1 - N2 - N3;
            us4 z = { 0, 0, 0, 0 };
            *(us4*)&hbuf[k * 4] = z;
        }
    }
}

// Zero the 512 per-WG barrier flags (128B-spaced; 16384 uints = 64 KB).
// Runs between k_gemm_xg (last reader of e_b, which the flags overlay) and
// k_recur. Kernel-end writeback makes the zeros visible at the MALL.
__global__ void k_zero_bar(unsigned int* bar) {
    bar[blockIdx.x * 256 + threadIdx.x] = 0u;
}

// ---------------------------------------------------------------------------
// Phase A: xg[m][g] = E[m][:] . Wih[g][:] + bih[g]   (bt-GEMM, m97 structure)
// grid (64, 24), 256 threads, 128x128 tile, BK=32.
// ---------------------------------------------------------------------------
__global__ __launch_bounds__(256) void k_gemm_xg(const ushort_t* __restrict__ A,
                                                 const ushort_t* __restrict__ Bm,
                                                 const float* __restrict__ bih,
                                                 ushort_t* __restrict__ xg) {
    __shared__ __align__(16) ushort_t Al[128 * 32];
    __shared__ __align__(16) ushort_t Bl[128 * 32];
    const int tid = threadIdx.x;
    const int m0 = blockIdx.x * 128, n0 = blockIdx.y * 128;
    const int wid = tid >> 6, lane = tid & 63;
    const int wm = wid & 1, wn = wid >> 1;
    const int lr = lane & 15, lq = lane >> 4;
    floatx4 acc[4][4] = {};
    for (int kb = 0; kb < KA / 32; ++kb) {
        const int k0 = kb * 32;
        #pragma unroll
        for (int j = 0; j < 2; ++j) {
            int c = j * 256 + tid;          // 512 16B chunks per matrix
            int row = c >> 2, k8 = c & 3;
            gload_lds16(A  + (size_t)(m0 + row) * KA + k0 + k8 * 8, &Al[c * 8]);
            gload_lds16(Bm + (size_t)(n0 + row) * KA + k0 + k8 * 8, &Bl[c * 8]);
        }
        __syncthreads();
        bf16x8 af[4], bf[4];
        #pragma unroll
        for (int i = 0; i < 4; ++i) af[i] = *(const bf16x8*)&Al[(wm * 64 + i * 16 + lr) * 32 + lq * 8];
        #pragma unroll
        for (int j = 0; j < 4; ++j) bf[j] = *(const bf16x8*)&Bl[(wn * 64 + j * 16 + lr) * 32 + lq * 8];
        #pragma unroll
        for (int i = 0; i < 4; ++i)
            #pragma unroll
            for (int j = 0; j < 4; ++j)
                acc[i][j] = mfma16(af[i], bf[j], acc[i][j]);
        __syncthreads();
    }
    #pragma unroll
    for (int i = 0; i < 4; ++i) {
        int grow = m0 + wm * 64 + i * 16 + lq * 4;
        #pragma unroll
        for (int j = 0; j < 4; ++j) {
            int gcol = n0 + wn * 64 + j * 16 + lr;
            float bv = bih[gcol];
            #pragma unroll
            for (int r = 0; r < 4; ++r)
                xg[(size_t)(grow + r) * G3 + gcol] = f2bf(acc[i][j][r] + bv);
        }
    }
}

// ---------------------------------------------------------------------------
// Recurrence: PLAIN-launched persistent kernel, 512 WGs x 256 thr, 2/CU
// (so a CU always has a second WG to compute while one stalls on MALL/poll).
// WG w: slab s = w>>3 (16 h-cols), group g = w&7 (16 batch rows; m=16 fills
// one MFMA m-tile exactly). Per wave: 3 n-tiles (r,z,n gates) x 8 K-chunks
// = 24 MFMAs, K split 4-ways across waves.
// Sync: per-WG flag (value = completed steps). A wave polls ONLY its 16
// producer WGs (the writers of its K-slice cols). WAR safety: h-writes are
// behind the WG syncthreads, which is behind all 4 waves' polls = all 64
// group WGs >= t, so a fast WG cannot overwrite data a laggard still reads.
// h_old is carried in a register (each gate thread re-reads its own write);
// xg for step t+1 is prefetched after the flag publish (hidden in the poll).
// ---------------------------------------------------------------------------
__global__ __launch_bounds__(256, 2) void k_recur(const ushort_t* __restrict__ xg,
                                                  const ushort_t* __restrict__ whh,
                                                  const float* __restrict__ bhh,
                                                  const int*   __restrict__ slen,
                                                  ushort_t* __restrict__ hbuf,
                                                  float* __restrict__ finalbuf,
                                                  unsigned int* __restrict__ bar) {
    __shared__ float P[12 * 288];            // K-partials: [kq][nt][16][16], stride 18
    const int tid = threadIdx.x, lane = tid & 63, kq = tid >> 6;
    const int w = blockIdx.x, s = w >> 3, g = w & 7;
    const int lr = lane & 15, lq = lane >> 4;
    // gate-phase coords: one h element per thread
    const int ri = tid >> 4, j = tid & 15;
    const int bg = 16 * g + ri;              // batch row
    const int gcol = 16 * s + j;             // h column
    unsigned int* myflag = bar + w * 32;     // 128B-spaced per-WG flag

    // --- hoisted invariants
    const int sl = slen[bg];
    const float bRv = bhh[gcol];
    const float bZv = bhh[H_SZ + gcol];
    const float bNv = bhh[2 * H_SZ + gcol];

    // --- this wave's w_hh B-fragments (static across steps, 96 VGPRs)
    bf16x8 Bf[3][8];
    #pragma unroll
    for (int nt = 0; nt < 3; ++nt) {
        const ushort_t* wrow = whh + (size_t)(nt * H_SZ + s * 16 + lr) * H_SZ;
        #pragma unroll
        for (int i = 0; i < 8; ++i)
            Bf[nt][i] = *(const bf16x8*)(wrow + kq * 256 + i * 32 + lq * 8);
    }

    union AF { unsigned long long u[2]; bf16x8 v; };

    // --- registers carried across steps
    float hold = 0.0f;                       // h[t][bg][gcol] — self-written
    const ushort_t* xgp = xg + (size_t)bg * T_SZ * G3 + gcol;
    unsigned short xr = xgp[0];              // prefetched xg for t=0
    unsigned short xz = xgp[H_SZ];
    unsigned short xn = xgp[2 * H_SZ];

    for (int t = 0; t < 64; ++t) {
        const ushort_t* hrd = hbuf + (t & 1) * (B_SZ * H_SZ);
        ushort_t*       hwr = hbuf + ((t + 1) & 1) * (B_SZ * H_SZ);

        // --- wave-level producer poll: wave kq needs h cols [256kq,256kq+256)
        //     = slabs s' in [16kq, 16kq+16) of group g. (t=0: trivially true.)
        if (lane < 16) {
            const unsigned int* fl = bar + (size_t)(((16 * kq + lane) << 3) + g) * 32;
            while (__hip_atomic_load(fl, __ATOMIC_RELAXED,
                                     __HIP_MEMORY_SCOPE_SYSTEM) < (unsigned int)t) {}
        }

        // --- A-fragments straight from the MALL (system-scope = sc0 sc1,
        //     L1/L2-bypassing, vmcnt-tracked). Lane (lr,lq) of wave kq owns
        //     h[16g+lr][256kq+32i+8lq ..+8].
        AF af[8];
        #pragma unroll
        for (int i = 0; i < 8; ++i) {
            const ushort_t* p = hrd + (size_t)(16 * g + lr) * H_SZ
                              + 256 * kq + 32 * i + 8 * lq;
            af[i].u[0] = __hip_atomic_load((const unsigned long long*)p,
                           __ATOMIC_RELAXED, __HIP_MEMORY_SCOPE_SYSTEM);
            af[i].u[1] = __hip_atomic_load((const unsigned long long*)(p + 4),
                           __ATOMIC_RELAXED, __HIP_MEMORY_SCOPE_SYSTEM);
        }

        // --- MFMA: 24 per wave (3 gates x 8 K-chunks)
        floatx4 acc[3] = {};
        #pragma unroll
        for (int i = 0; i < 8; ++i)
            #pragma unroll
            for (int nt = 0; nt < 3; ++nt)
                acc[nt] = mfma16(af[i].v, Bf[nt][i], acc[nt]);

        // --- K-partials to LDS (C-layout: col=lr, row=lq*4+r; stride 18)
        #pragma unroll
        for (int nt = 0; nt < 3; ++nt)
            #pragma unroll
            for (int r = 0; r < 4; ++r)
                P[(kq * 3 + nt) * 288 + (lq * 4 + r) * 18 + lr] = acc[nt][r];
        __syncthreads();

        // --- gate phase: one h element per thread
        {
            float hg[3];
            #pragma unroll
            for (int nt = 0; nt < 3; ++nt)
                hg[nt] = P[nt * 288 + ri * 18 + j]
                       + P[(3 + nt) * 288 + ri * 18 + j]
                       + P[(6 + nt) * 288 + ri * 18 + j]
                       + P[(9 + nt) * 288 + ri * 18 + j];
            float rr = fsigmoid(bf2f(xr) + hg[0] + bRv);
            float zz = fsigmoid(bf2f(xz) + hg[1] + bZv);
            float nn = ftanh(bf2f(xn) + rr * (hg[2] + bNv));
            float hnew = (1.0f - zz) * nn + zz * hold;
            hold = hnew;
            __hip_atomic_store(hwr + (size_t)bg * H_SZ + gcol, f2bf(hnew),
                               __ATOMIC_RELAXED, __HIP_MEMORY_SCOPE_SYSTEM);
            if (sl - 1 == t) finalbuf[(size_t)bg * H_SZ + gcol] = hnew;
        }

        if (t != 63) {
            // publish: drain write-through h stores at the MALL (R7-proven),
            // collect all waves, then one fire-and-forget flag store.
            asm volatile("s_waitcnt vmcnt(0)" ::: "memory");
            __syncthreads();
            if (tid == 0)
                __hip_atomic_store(myflag, (unsigned int)(t + 1),
                                   __ATOMIC_RELAXED, __HIP_MEMORY_SCOPE_SYSTEM);
            // prefetch next step's xg; latency hidden inside the next poll
            xr = xgp[(size_t)(t + 1) * G3];
            xz = xgp[(size_t)(t + 1) * G3 + H_SZ];
            xn = xgp[(size_t)(t + 1) * G3 + 2 * H_SZ];
        }
    }
}

// ---------------------------------------------------------------------------
// Final L2-normalize per batch row.
// ---------------------------------------------------------------------------
__global__ __launch_bounds__(256) void k_norm(const float* __restrict__ finalbuf,
                                              float* __restrict__ out) {
    const int b = blockIdx.x, tid = threadIdx.x;
    const float4 v = ((const float4*)(finalbuf + (size_t)b * H_SZ))[tid];
    float ss = v.x * v.x + v.y * v.y + v.z * v.z + v.w * v.w;
    #pragma unroll
    for (int off = 32; off > 0; off >>= 1) ss += __shfl_down(ss, off);
    __shared__ float red[4];
    const int wid = tid >> 6, lane = tid & 63;
    if (lane == 0) red[wid] = ss;
    __syncthreads();
    const float total = red[0] + red[1] + red[2] + red[3];
    const float inv = 1.0f / sqrtf(total);
    float4 o;
    o.x = v.x * inv; o.y = v.y * inv; o.z = v.z * inv; o.w = v.w * inv;
    ((float4*)(out + (size_t)b * H_SZ))[tid] = o;
}

extern "C" void kernel_launch(void* const* d_in, const int* in_sizes, int n_in,
                              void* d_out, int out_size, void* d_ws, size_t ws_size,
                              hipStream_t stream) {
    const int*   sent = (const int*)d_in[0];
    const int*   slen = (const int*)d_in[1];
    const float* emb  = (const float*)d_in[2];
    const float* wih  = (const float*)d_in[3];
    const float* whh  = (const float*)d_in[4];
    const float* bih  = (const float*)d_in[5];
    const float* bhh  = (const float*)d_in[6];
    float* out = (float*)d_out;
    char* ws = (char*)d_ws;

    // workspace layout (bytes)
    ushort_t* e_b      = (ushort_t*)(ws);                 //  8,388,608  (8192x512 bf16)
    ushort_t* wih_b    = (ushort_t*)(ws + 8388608);       //  3,145,728
    ushort_t* whh_b    = (ushort_t*)(ws + 11534336);      //  6,291,456
    ushort_t* xg       = (ushort_t*)(ws + 17825792);      // 50,331,648  (8192x3072 bf16)
    ushort_t* hbuf     = (ushort_t*)(ws + 68157440);      //    524,288  (2 x 128x1024 bf16)
    float*    finalbuf = (float*)   (ws + 68681728);      //    524,288  (128x1024 f32)
    // barrier flags overlay e_b[0..32767] (64 KB) — e_b dead after k_gemm_xg
    unsigned int* bar  = (unsigned int*)(ws);

    hipLaunchKernelGGL(k_prep, dim3(1024), dim3(256), 0, stream,
                       wih, whh, emb, sent, wih_b, whh_b, e_b, hbuf);
    hipLaunchKernelGGL(k_gemm_xg, dim3(64, 24), dim3(256), 0, stream,
                       e_b, wih_b, bih, xg);
    hipLaunchKernelGGL(k_zero_bar, dim3(64), dim3(256), 0, stream, bar);
    // PLAIN launch: 512 WGs, 2/CU — co-resident by capacity (13.8 KB LDS,
    // ~170 VGPR with __launch_bounds__(256,2)).
    hipLaunchKernelGGL(k_recur, dim3(512), dim3(256), 0, stream,
                       xg, whh_b, bhh, slen, hbuf, finalbuf, bar);
    hipLaunchKernelGGL(k_norm, dim3(128), dim3(256), 0, stream, finalbuf, out);
}